// Round 2
// baseline (5493.790 us; speedup 1.0000x reference)
//
#include <hip/hip_runtime.h>

// ---------------------------------------------------------------------------
// C[M,N] = A[M,K] * W[N,K]^T   (fp32 in/out/accum)
// 64x64 tile, BK=16, 256 threads, 4x4 per thread.
// ---------------------------------------------------------------------------
__global__ __launch_bounds__(256) void gemm_bt(
    const float* __restrict__ A, int lda,
    const float* __restrict__ W, int ldw,
    float* __restrict__ C, int ldc,
    int M, int N, int K) {
  __shared__ float As[16][65];   // [k][m], +1 pad
  __shared__ float Ws[16][65];   // [k][n]
  int tid = threadIdx.x;
  int tx = tid & 15, ty = tid >> 4;
  int bm = blockIdx.y * 64, bn = blockIdx.x * 64;
  float acc[4][4] = {};
  for (int k0 = 0; k0 < K; k0 += 16) {
#pragma unroll
    for (int i = 0; i < 4; i++) {
      int e = tid + 256 * i;         // 0..1023
      int r = e >> 4, c = e & 15;    // 16 consecutive lanes read 64B rows
      As[c][r] = A[(size_t)(bm + r) * lda + k0 + c];
      Ws[c][r] = W[(size_t)(bn + r) * ldw + k0 + c];
    }
    __syncthreads();
#pragma unroll
    for (int kk = 0; kk < 16; kk++) {
      float a[4], b[4];
#pragma unroll
      for (int i = 0; i < 4; i++) a[i] = As[kk][ty * 4 + i];
#pragma unroll
      for (int j = 0; j < 4; j++) b[j] = Ws[kk][tx * 4 + j];
#pragma unroll
      for (int i = 0; i < 4; i++)
#pragma unroll
        for (int j = 0; j < 4; j++) acc[i][j] += a[i] * b[j];
    }
    __syncthreads();
  }
#pragma unroll
  for (int i = 0; i < 4; i++) {
    size_t m = (size_t)(bm + ty * 4 + i);
#pragma unroll
    for (int j = 0; j < 4; j++)
      C[m * ldc + bn + tx * 4 + j] = acc[i][j];
  }
}

// ---------------------------------------------------------------------------
// RMSNorm over `width` elements of each row (row stride `stride`), in-place ok.
// ---------------------------------------------------------------------------
__global__ __launch_bounds__(256) void rmsnorm_k(
    const float* __restrict__ in, const float* __restrict__ w,
    float* __restrict__ out, int width, int stride) {
  int row = blockIdx.x;
  const float* p = in + (size_t)row * stride;
  float* o = out + (size_t)row * stride;
  float ss = 0.f;
  for (int i = threadIdx.x; i < width; i += 256) { float v = p[i]; ss += v * v; }
  for (int off = 32; off > 0; off >>= 1) ss += __shfl_down(ss, off);
  __shared__ float red[4];
  if ((threadIdx.x & 63) == 0) red[threadIdx.x >> 6] = ss;
  __syncthreads();
  float inv = rsqrtf((red[0] + red[1] + red[2] + red[3]) / (float)width + 1e-6f);
  for (int i = threadIdx.x; i < width; i += 256)
    o[i] = p[i] * inv * w[i];
}

// ---------------------------------------------------------------------------
// RoPE (in-place): out[i] = x[i]*c[i] - x[i+32]*s[i],
// out[i+32] = x[i+32]*c[i+32] + x[i]*s[i+32].  grid=(tokens, heads), block=32.
// ---------------------------------------------------------------------------
__global__ void rope_k(float* __restrict__ base, int row_stride, int head_stride,
                       int head_off, const float* __restrict__ cosb,
                       const float* __restrict__ sinb, int S) {
  int t = blockIdx.x, h = blockIdx.y, i = threadIdx.x;  // i in [0,32)
  int pos = t % S;
  float* p = base + (size_t)t * row_stride + h * head_stride + head_off;
  float c1 = cosb[pos * 64 + i];
  float c2 = cosb[pos * 64 + i + 32];
  float s1 = sinb[pos * 64 + i];
  float s2 = sinb[pos * 64 + i + 32];
  float x1 = p[i], x2 = p[i + 32];
  p[i]      = x1 * c1 - x2 * s1;
  p[i + 32] = x2 * c2 + x1 * s2;
}

// ---------------------------------------------------------------------------
// Flash-style causal attention.
// q   : [B*S, 3072]  (16 heads * 192, rope already applied to d>=128)
// kvb : [B*S, 4096]  (16 heads * (k_nope 128 | v 128))
// kpe : [B*S, 576]   (cols 512..575 hold roped k_pe, shared by all heads)
// out : [B*S, 2048]  (16 heads * 128)
// One block: 16 q rows of one (b,h); loop over 32-key tiles. 256 threads.
// ---------------------------------------------------------------------------
#define BQ 16
__global__ __launch_bounds__(256) void attn_k(
    const float* __restrict__ q, const float* __restrict__ kvb,
    const float* __restrict__ kpe, float* __restrict__ out, int S) {
  int qt = blockIdx.x, h = blockIdx.y, b = blockIdx.z;
  int tid = threadIdx.x;
  __shared__ float Qs[BQ][196];   // 192 used; 196 keeps rows 16B-aligned
  __shared__ float Ks[32][196];
  __shared__ float Vs[32][128];
  __shared__ float Ss[BQ][33];
  __shared__ float m_s[BQ], l_s[BQ], a_s[BQ];
  int qbase = qt * BQ;

  for (int e = tid; e < BQ * 192; e += 256) {
    int r = e / 192, d = e % 192;
    Qs[r][d] = q[(size_t)(b * S + qbase + r) * 3072 + h * 192 + d];
  }
  if (tid < BQ) { m_s[tid] = -3e38f; l_s[tid] = 0.f; }
  float o[8] = {};
  int r_own = tid >> 4;            // 0..15
  int c_base = (tid & 15) * 4;     // cols c_base + 64*i, i=0,1
  const float scale = 0.07216878364870323f;  // 192^-0.5
  __syncthreads();

  int ntiles = (qbase + BQ - 1) / 32 + 1;    // kbase <= qbase+BQ-1 always
  for (int kt = 0; kt < ntiles; kt++) {
    int kbase = kt * 32;
    for (int e = tid; e < 32 * 192; e += 256) {
      int j = e / 192, d = e % 192;
      size_t tk = (size_t)(b * S + kbase + j);
      Ks[j][d] = (d < 128) ? kvb[tk * 4096 + h * 256 + d]
                           : kpe[tk * 576 + 512 + (d - 128)];
    }
    for (int e = tid; e < 32 * 128; e += 256) {
      int j = e >> 7, d = e & 127;
      size_t tk = (size_t)(b * S + kbase + j);
      Vs[j][d] = kvb[tk * 4096 + h * 256 + 128 + d];
    }
    __syncthreads();
    {  // scores: each thread 2 (qr,kc) pairs
      int qr = tid & 15;
      int kc0 = (tid >> 4) * 2;
      float s0 = 0.f, s1 = 0.f;
      for (int d = 0; d < 192; d += 4) {
        float4 qv = *(const float4*)&Qs[qr][d];
        float4 k0 = *(const float4*)&Ks[kc0 + 0][d];
        float4 k1 = *(const float4*)&Ks[kc0 + 1][d];
        s0 += qv.x * k0.x + qv.y * k0.y + qv.z * k0.z + qv.w * k0.w;
        s1 += qv.x * k1.x + qv.y * k1.y + qv.z * k1.z + qv.w * k1.w;
      }
      float sv[2] = {s0, s1};
#pragma unroll
      for (int jj = 0; jj < 2; jj++) {
        float s = sv[jj] * scale;
        if (kbase + kc0 + jj > qbase + qr) s = -3e38f;  // causal mask
        Ss[qr][kc0 + jj] = s;
      }
    }
    __syncthreads();
    if (tid < BQ) {  // online-softmax row update
      int r = tid;
      float mold = m_s[r];
      float mt = mold;
#pragma unroll
      for (int j = 0; j < 32; j++) mt = fmaxf(mt, Ss[r][j]);
      float al = __expf(mold - mt);
      float ssum = 0.f;
#pragma unroll
      for (int j = 0; j < 32; j++) {
        float pv = __expf(Ss[r][j] - mt);
        Ss[r][j] = pv;
        ssum += pv;
      }
      l_s[r] = l_s[r] * al + ssum;
      m_s[r] = mt;
      a_s[r] = al;
    }
    __syncthreads();
    {  // PV accumulate
      float al = a_s[r_own];
#pragma unroll
      for (int i = 0; i < 8; i++) o[i] *= al;
      for (int j = 0; j < 32; j++) {
        float pv = Ss[r_own][j];
#pragma unroll
        for (int i = 0; i < 2; i++) {
          float4 vv = *(const float4*)&Vs[j][c_base + 64 * i];
          o[i * 4 + 0] += pv * vv.x;
          o[i * 4 + 1] += pv * vv.y;
          o[i * 4 + 2] += pv * vv.z;
          o[i * 4 + 3] += pv * vv.w;
        }
      }
    }
    __syncthreads();
  }
  float inv_l = 1.f / l_s[r_own];
  size_t t = (size_t)(b * S + qbase + r_own);
#pragma unroll
  for (int i = 0; i < 2; i++)
#pragma unroll
    for (int jj = 0; jj < 4; jj++)
      out[t * 2048 + h * 128 + c_base + 64 * i + jj] = o[i * 4 + jj] * inv_l;
}

// ---------------------------------------------------------------------------
extern "C" void kernel_launch(void* const* d_in, const int* in_sizes, int n_in,
                              void* d_out, int out_size, void* d_ws, size_t ws_size,
                              hipStream_t stream) {
  (void)in_sizes; (void)n_in; (void)out_size; (void)ws_size;
  const float* x     = (const float*)d_in[0];
  const float* cosb  = (const float*)d_in[1];
  const float* sinb  = (const float*)d_in[2];
  const float* wq_a  = (const float*)d_in[3];
  const float* qnw   = (const float*)d_in[4];
  const float* wq_b  = (const float*)d_in[5];
  const float* wkv_a = (const float*)d_in[6];
  const float* kvnw  = (const float*)d_in[7];
  const float* wkv_b = (const float*)d_in[8];
  const float* wo    = (const float*)d_in[9];
  float* out = (float*)d_out;
  const int B = 2, S = 2048, T = B * S;

  char* wsb = (char*)d_ws;
  size_t off = 0;
  float* qa  = (float*)(wsb + off); off += (size_t)T * 1536 * 4;  // q lora
  float* kv  = (float*)(wsb + off); off += (size_t)T * 576 * 4;   // kv lora + k_pe
  float* qf  = (float*)(wsb + off); off += (size_t)T * 3072 * 4;  // full q
  float* kvb = (float*)(wsb + off); off += (size_t)T * 4096 * 4;  // k_nope|v per head
  float* at  = (float*)(wsb + off); off += (size_t)T * 2048 * 4;  // attn out

  // 1) qa = x @ wq_a^T            [T,1536]
  gemm_bt<<<dim3(1536 / 64, T / 64), 256, 0, stream>>>(x, 2048, wq_a, 2048, qa, 1536, T, 1536, 2048);
  // 2) kv = x @ wkv_a^T           [T,576]
  gemm_bt<<<dim3(576 / 64, T / 64), 256, 0, stream>>>(x, 2048, wkv_a, 2048, kv, 576, T, 576, 2048);
  // 3) rmsnorm(qa) in-place
  rmsnorm_k<<<T, 256, 0, stream>>>(qa, qnw, qa, 1536, 1536);
  // 4) rmsnorm(kv_c) in-place; rope(k_pe) in-place
  rmsnorm_k<<<T, 256, 0, stream>>>(kv, kvnw, kv, 512, 576);
  rope_k<<<dim3(T, 1), 32, 0, stream>>>(kv, 576, 0, 512, cosb, sinb, S);
  // 5) q = qa_norm @ wq_b^T       [T,3072]; then rope q_pe per head
  gemm_bt<<<dim3(3072 / 64, T / 64), 256, 0, stream>>>(qa, 1536, wq_b, 1536, qf, 3072, T, 3072, 1536);
  rope_k<<<dim3(T, 16), 32, 0, stream>>>(qf, 3072, 192, 128, cosb, sinb, S);
  // 6) kvb = kv_c_norm @ wkv_b^T  [T,4096]  (A row stride 576, K=512)
  gemm_bt<<<dim3(4096 / 64, T / 64), 256, 0, stream>>>(kv, 576, wkv_b, 512, kvb, 4096, T, 4096, 512);
  // 7) attention -> at [T,2048]
  attn_k<<<dim3(S / BQ, 16, B), 256, 0, stream>>>(qf, kvb, kv, at, S);
  // 8) out = at @ wo^T            [T,2048] fp32
  gemm_bt<<<dim3(2048 / 64, T / 64), 256, 0, stream>>>(at, 2048, wo, 2048, out, 2048, T, 2048, 2048);
}

// Round 3
// 3350.421 us; speedup vs baseline: 1.6397x; 1.6397x over previous
//
#include <hip/hip_runtime.h>

typedef unsigned short u16;
typedef __attribute__((ext_vector_type(8))) short short8;   // 8 bf16 = 4 VGPRs
typedef __attribute__((ext_vector_type(4))) float floatx4;

__device__ __forceinline__ float bf2f(u16 u) {
  union { unsigned int i; float f; } v; v.i = ((unsigned int)u) << 16; return v.f;
}
__device__ __forceinline__ u16 f2bf(float f) {
  union { float f; unsigned int i; } v; v.f = f;
  unsigned int u = v.i;
  u += 0x7fffu + ((u >> 16) & 1u);   // RNE
  return (u16)(u >> 16);
}

__device__ __forceinline__ void gld_lds16(const void* g, void* l) {
  __builtin_amdgcn_global_load_lds(
      (const __attribute__((address_space(1))) unsigned int*)g,
      (__attribute__((address_space(3))) unsigned int*)l, 16, 0, 0);
}

// ---------------------------------------------------------------------------
// fp32 -> bf16 repack (inputs are bf16-quantized fp32, so this is lossless)
// ---------------------------------------------------------------------------
__global__ __launch_bounds__(256) void f2b_k(const float* __restrict__ s,
                                             u16* __restrict__ d, long n) {
  long i = ((long)blockIdx.x * 256 + threadIdx.x) * 4;
  if (i + 3 < n) {
    float4 v = *(const float4*)(s + i);
    d[i + 0] = f2bf(v.x); d[i + 1] = f2bf(v.y);
    d[i + 2] = f2bf(v.z); d[i + 3] = f2bf(v.w);
  } else {
    for (; i < n; i++) d[i] = f2bf(s[i]);
  }
}

// pad rows beyond rows_src with zeros (for N=576 -> 640)
__global__ __launch_bounds__(256) void f2b_pad_k(const float* __restrict__ s,
                                                 u16* __restrict__ d,
                                                 int rows_src, int cols, int rows_dst) {
  long i = (long)blockIdx.x * 256 + threadIdx.x;
  long total = (long)rows_dst * cols;
  if (i < total) {
    long r = i / cols, c = i - r * cols;
    d[i] = (r < rows_src) ? f2bf(s[r * cols + c]) : (u16)0;
  }
}

// ---------------------------------------------------------------------------
// MFMA GEMM (m97 recipe): C[M,N] = A[M,K] * W[N,K]^T, bf16 in, fp32 acc.
// 128x128 block tile, BK=32, 256 threads = 4 waves (2x2), 64x64 per wave.
// OUT_F32=0 -> bf16 C, OUT_F32=1 -> fp32 C. M,N multiples of 128; K mult of 32.
// ---------------------------------------------------------------------------
template <int OUT_F32>
__global__ __launch_bounds__(256) void gemm_bt_mfma(
    const u16* __restrict__ A, int lda,
    const u16* __restrict__ W, int ldw,
    void* __restrict__ Cv, int ldc, int K) {
  __shared__ u16 Asm[128 * 32];
  __shared__ u16 Bsm[128 * 32];
  int tid = threadIdx.x;
  int lane = tid & 63, w = tid >> 6;
  int wm = (w >> 1) * 64, wn = (w & 1) * 64;
  int bm = blockIdx.y * 128, bn = blockIdx.x * 128;

  floatx4 acc[4][4];
#pragma unroll
  for (int i = 0; i < 4; i++)
#pragma unroll
    for (int j = 0; j < 4; j++) acc[i][j] = (floatx4){0.f, 0.f, 0.f, 0.f};

  int sr = lane >> 2;          // staging row within 16-row chunk
  int sc = (lane & 3) * 8;     // staging bf16 col offset (16B/lane)
  int fr = lane & 15;          // fragment m/n within 16
  int fq = (lane >> 4) * 8;    // fragment k offset within 32

  for (int k0 = 0; k0 < K; k0 += 32) {
#pragma unroll
    for (int c = 0; c < 2; c++) {
      int row = 32 * w + 16 * c + sr;
      gld_lds16(A + (size_t)(bm + row) * lda + k0 + sc, &Asm[(32 * w + 16 * c) * 32]);
      gld_lds16(W + (size_t)(bn + row) * ldw + k0 + sc, &Bsm[(32 * w + 16 * c) * 32]);
    }
    __syncthreads();
    short8 af[4], bfr[4];
#pragma unroll
    for (int i = 0; i < 4; i++)
      af[i] = *(const short8*)&Asm[(wm + i * 16 + fr) * 32 + fq];
#pragma unroll
    for (int j = 0; j < 4; j++)
      bfr[j] = *(const short8*)&Bsm[(wn + j * 16 + fr) * 32 + fq];
#pragma unroll
    for (int i = 0; i < 4; i++)
#pragma unroll
      for (int j = 0; j < 4; j++)
        acc[i][j] = __builtin_amdgcn_mfma_f32_16x16x32_bf16(af[i], bfr[j], acc[i][j], 0, 0, 0);
    __syncthreads();
  }

  int cr = (lane >> 4) * 4, cc = lane & 15;   // C/D: row=(lane>>4)*4+r, col=lane&15
#pragma unroll
  for (int i = 0; i < 4; i++)
#pragma unroll
    for (int j = 0; j < 4; j++) {
      int col = bn + wn + j * 16 + cc;
#pragma unroll
      for (int r = 0; r < 4; r++) {
        size_t row = (size_t)(bm + wm + i * 16 + cr + r);
        if (OUT_F32) ((float*)Cv)[row * ldc + col] = acc[i][j][r];
        else         ((u16*)Cv)[row * ldc + col] = f2bf(acc[i][j][r]);
      }
    }
}

// ---------------------------------------------------------------------------
// RMSNorm (bf16 data, fp32 norm weights, fp32 math)
// ---------------------------------------------------------------------------
__global__ __launch_bounds__(256) void rmsnorm_k(
    const u16* __restrict__ in, const float* __restrict__ w,
    u16* __restrict__ out, int width, int stride) {
  int row = blockIdx.x;
  const u16* p = in + (size_t)row * stride;
  u16* o = out + (size_t)row * stride;
  float ss = 0.f;
  for (int i = threadIdx.x; i < width; i += 256) { float v = bf2f(p[i]); ss += v * v; }
  for (int off = 32; off > 0; off >>= 1) ss += __shfl_down(ss, off);
  __shared__ float red[4];
  if ((threadIdx.x & 63) == 0) red[threadIdx.x >> 6] = ss;
  __syncthreads();
  float inv = rsqrtf((red[0] + red[1] + red[2] + red[3]) / (float)width + 1e-6f);
  for (int i = threadIdx.x; i < width; i += 256)
    o[i] = f2bf(bf2f(p[i]) * inv * w[i]);
}

// ---------------------------------------------------------------------------
// RoPE in-place (bf16 data, fp32 cos/sin). grid=(tokens, heads), block=32.
// ---------------------------------------------------------------------------
__global__ void rope_k(u16* __restrict__ base, int row_stride, int head_stride,
                       int head_off, const float* __restrict__ cosb,
                       const float* __restrict__ sinb, int S) {
  int t = blockIdx.x, h = blockIdx.y, i = threadIdx.x;  // i in [0,32)
  int pos = t % S;
  u16* p = base + (size_t)t * row_stride + h * head_stride + head_off;
  float c1 = cosb[pos * 64 + i];
  float c2 = cosb[pos * 64 + i + 32];
  float s1 = sinb[pos * 64 + i];
  float s2 = sinb[pos * 64 + i + 32];
  float x1 = bf2f(p[i]), x2 = bf2f(p[i + 32]);
  p[i]      = f2bf(x1 * c1 - x2 * s1);
  p[i + 32] = f2bf(x2 * c2 + x1 * s2);
}

// ---------------------------------------------------------------------------
// Flash-style causal attention (bf16 I/O, fp32 math).
// q: [T,3072] kvb: [T,4096] kpe: [T,640] (cols 512..575) out: [T,2048]
// ---------------------------------------------------------------------------
#define BQ 16
__global__ __launch_bounds__(256) void attn_k(
    const u16* __restrict__ q, const u16* __restrict__ kvb,
    const u16* __restrict__ kpe, u16* __restrict__ out, int S) {
  int qt = blockIdx.x, h = blockIdx.y, b = blockIdx.z;
  int tid = threadIdx.x;
  __shared__ float Qs[BQ][196];
  __shared__ float Ks[32][196];
  __shared__ float Vs[32][128];
  __shared__ float Ss[BQ][33];
  __shared__ float m_s[BQ], l_s[BQ], a_s[BQ];
  int qbase = qt * BQ;

  for (int e = tid; e < BQ * 192; e += 256) {
    int r = e / 192, d = e % 192;
    Qs[r][d] = bf2f(q[(size_t)(b * S + qbase + r) * 3072 + h * 192 + d]);
  }
  if (tid < BQ) { m_s[tid] = -3e38f; l_s[tid] = 0.f; }
  float o[8] = {};
  int r_own = tid >> 4;
  int c_base = (tid & 15) * 4;
  const float scale = 0.07216878364870323f;  // 192^-0.5
  __syncthreads();

  int ntiles = (qbase + BQ - 1) / 32 + 1;
  for (int kt = 0; kt < ntiles; kt++) {
    int kbase = kt * 32;
    for (int e = tid; e < 32 * 192; e += 256) {
      int j = e / 192, d = e % 192;
      size_t tk = (size_t)(b * S + kbase + j);
      Ks[j][d] = (d < 128) ? bf2f(kvb[tk * 4096 + h * 256 + d])
                           : bf2f(kpe[tk * 640 + 512 + (d - 128)]);
    }
    for (int e = tid; e < 32 * 128; e += 256) {
      int j = e >> 7, d = e & 127;
      size_t tk = (size_t)(b * S + kbase + j);
      Vs[j][d] = bf2f(kvb[tk * 4096 + h * 256 + 128 + d]);
    }
    __syncthreads();
    {
      int qr = tid & 15;
      int kc0 = (tid >> 4) * 2;
      float s0 = 0.f, s1 = 0.f;
      for (int d = 0; d < 192; d += 4) {
        float4 qv = *(const float4*)&Qs[qr][d];
        float4 k0 = *(const float4*)&Ks[kc0 + 0][d];
        float4 k1 = *(const float4*)&Ks[kc0 + 1][d];
        s0 += qv.x * k0.x + qv.y * k0.y + qv.z * k0.z + qv.w * k0.w;
        s1 += qv.x * k1.x + qv.y * k1.y + qv.z * k1.z + qv.w * k1.w;
      }
      float sv[2] = {s0, s1};
#pragma unroll
      for (int jj = 0; jj < 2; jj++) {
        float s = sv[jj] * scale;
        if (kbase + kc0 + jj > qbase + qr) s = -3e38f;
        Ss[qr][kc0 + jj] = s;
      }
    }
    __syncthreads();
    if (tid < BQ) {
      int r = tid;
      float mold = m_s[r];
      float mt = mold;
#pragma unroll
      for (int j = 0; j < 32; j++) mt = fmaxf(mt, Ss[r][j]);
      float al = __expf(mold - mt);
      float ssum = 0.f;
#pragma unroll
      for (int j = 0; j < 32; j++) {
        float pv = __expf(Ss[r][j] - mt);
        Ss[r][j] = pv;
        ssum += pv;
      }
      l_s[r] = l_s[r] * al + ssum;
      m_s[r] = mt;
      a_s[r] = al;
    }
    __syncthreads();
    {
      float al = a_s[r_own];
#pragma unroll
      for (int i = 0; i < 8; i++) o[i] *= al;
      for (int j = 0; j < 32; j++) {
        float pv = Ss[r_own][j];
#pragma unroll
        for (int i = 0; i < 2; i++) {
          float4 vv = *(const float4*)&Vs[j][c_base + 64 * i];
          o[i * 4 + 0] += pv * vv.x;
          o[i * 4 + 1] += pv * vv.y;
          o[i * 4 + 2] += pv * vv.z;
          o[i * 4 + 3] += pv * vv.w;
        }
      }
    }
    __syncthreads();
  }
  float inv_l = 1.f / l_s[r_own];
  size_t t = (size_t)(b * S + qbase + r_own);
#pragma unroll
  for (int i = 0; i < 2; i++)
#pragma unroll
    for (int jj = 0; jj < 4; jj++)
      out[t * 2048 + h * 128 + c_base + 64 * i + jj] = f2bf(o[i * 4 + jj] * inv_l);
}

// ---------------------------------------------------------------------------
extern "C" void kernel_launch(void* const* d_in, const int* in_sizes, int n_in,
                              void* d_out, int out_size, void* d_ws, size_t ws_size,
                              hipStream_t stream) {
  (void)in_sizes; (void)n_in; (void)out_size; (void)ws_size;
  const float* x     = (const float*)d_in[0];
  const float* cosb  = (const float*)d_in[1];
  const float* sinb  = (const float*)d_in[2];
  const float* wq_a  = (const float*)d_in[3];
  const float* qnw   = (const float*)d_in[4];
  const float* wq_b  = (const float*)d_in[5];
  const float* wkv_a = (const float*)d_in[6];
  const float* kvnw  = (const float*)d_in[7];
  const float* wkv_b = (const float*)d_in[8];
  const float* wo    = (const float*)d_in[9];
  float* out = (float*)d_out;
  const int B = 2, S = 2048, T = B * S;

  char* wsb = (char*)d_ws;
  size_t off = 0;
  u16* xb   = (u16*)(wsb + off); off += (size_t)T * 2048 * 2;
  u16* wqab = (u16*)(wsb + off); off += (size_t)1536 * 2048 * 2;
  u16* wqbb = (u16*)(wsb + off); off += (size_t)3072 * 1536 * 2;
  u16* wkab = (u16*)(wsb + off); off += (size_t)640 * 2048 * 2;   // padded 576->640
  u16* wkbb = (u16*)(wsb + off); off += (size_t)4096 * 512 * 2;
  u16* wob  = (u16*)(wsb + off); off += (size_t)2048 * 2048 * 2;
  u16* qa   = (u16*)(wsb + off); off += (size_t)T * 1536 * 2;
  u16* kvp  = (u16*)(wsb + off); off += (size_t)T * 640 * 2;
  u16* qf   = (u16*)(wsb + off); off += (size_t)T * 3072 * 2;
  u16* kvb  = (u16*)(wsb + off); off += (size_t)T * 4096 * 2;
  u16* at   = (u16*)(wsb + off); off += (size_t)T * 2048 * 2;

  auto conv = [&](const float* s, u16* d, long n) {
    f2b_k<<<(int)((n / 4 + 255) / 256), 256, 0, stream>>>(s, d, n);
  };
  conv(x, xb, (long)T * 2048);
  conv(wq_a, wqab, (long)1536 * 2048);
  conv(wq_b, wqbb, (long)3072 * 1536);
  f2b_pad_k<<<(int)(((long)640 * 2048 + 255) / 256), 256, 0, stream>>>(wkv_a, wkab, 576, 2048, 640);
  conv(wkv_b, wkbb, (long)4096 * 512);
  conv(wo, wob, (long)2048 * 2048);

  // 1) qa = xb @ wq_a^T  [T,1536]
  gemm_bt_mfma<0><<<dim3(1536 / 128, T / 128), 256, 0, stream>>>(xb, 2048, wqab, 2048, qa, 1536, 2048);
  // 2) kvp = xb @ wkv_a^T [T,640] (cols >=576 are zero)
  gemm_bt_mfma<0><<<dim3(640 / 128, T / 128), 256, 0, stream>>>(xb, 2048, wkab, 2048, kvp, 640, 2048);
  // 3) rmsnorm(qa) in-place
  rmsnorm_k<<<T, 256, 0, stream>>>(qa, qnw, qa, 1536, 1536);
  // 4) rmsnorm(kv_c) in-place; rope(k_pe) in-place
  rmsnorm_k<<<T, 256, 0, stream>>>(kvp, kvnw, kvp, 512, 640);
  rope_k<<<dim3(T, 1), 32, 0, stream>>>(kvp, 640, 0, 512, cosb, sinb, S);
  // 5) qf = qa @ wq_b^T [T,3072]; rope q_pe per head
  gemm_bt_mfma<0><<<dim3(3072 / 128, T / 128), 256, 0, stream>>>(qa, 1536, wqbb, 1536, qf, 3072, 1536);
  rope_k<<<dim3(T, 16), 32, 0, stream>>>(qf, 3072, 192, 128, cosb, sinb, S);
  // 6) kvb = kv_norm @ wkv_b^T [T,4096] (A stride 640, K=512)
  gemm_bt_mfma<0><<<dim3(4096 / 128, T / 128), 256, 0, stream>>>(kvp, 640, wkbb, 512, kvb, 4096, 512);
  // 7) attention -> at [T,2048]
  attn_k<<<dim3(S / BQ, 16, B), 256, 0, stream>>>(qf, kvb, kvp, at, S);
  // 8) out = at @ wo^T [T,2048] fp32
  gemm_bt_mfma<1><<<dim3(2048 / 128, T / 128), 256, 0, stream>>>(at, 2048, wob, 2048, out, 2048, 2048);
}

// Round 4
// 743.414 us; speedup vs baseline: 7.3900x; 4.5068x over previous
//
#include <hip/hip_runtime.h>

typedef unsigned short u16;
typedef __attribute__((ext_vector_type(8))) short short8;   // 8 bf16 = 4 VGPRs
typedef __attribute__((ext_vector_type(4))) float floatx4;

__device__ __forceinline__ float bf2f(u16 u) {
  union { unsigned int i; float f; } v; v.i = ((unsigned int)u) << 16; return v.f;
}
__device__ __forceinline__ u16 f2bf(float f) {
  union { float f; unsigned int i; } v; v.f = f;
  unsigned int u = v.i;
  u += 0x7fffu + ((u >> 16) & 1u);   // RNE
  return (u16)(u >> 16);
}

__device__ __forceinline__ void gld_lds16(const void* g, void* l) {
  __builtin_amdgcn_global_load_lds(
      (const __attribute__((address_space(1))) unsigned int*)g,
      (__attribute__((address_space(3))) unsigned int*)l, 16, 0, 0);
}

// ---------------------------------------------------------------------------
// fp32 -> bf16 repack (inputs are bf16-quantized fp32, so this is lossless)
// ---------------------------------------------------------------------------
__global__ __launch_bounds__(256) void f2b_k(const float* __restrict__ s,
                                             u16* __restrict__ d, long n) {
  long i = ((long)blockIdx.x * 256 + threadIdx.x) * 4;
  if (i + 3 < n) {
    float4 v = *(const float4*)(s + i);
    d[i + 0] = f2bf(v.x); d[i + 1] = f2bf(v.y);
    d[i + 2] = f2bf(v.z); d[i + 3] = f2bf(v.w);
  } else {
    for (; i < n; i++) d[i] = f2bf(s[i]);
  }
}

__global__ __launch_bounds__(256) void f2b_pad_k(const float* __restrict__ s,
                                                 u16* __restrict__ d,
                                                 int rows_src, int cols, int rows_dst) {
  long i = (long)blockIdx.x * 256 + threadIdx.x;
  long total = (long)rows_dst * cols;
  if (i < total) {
    long r = i / cols, c = i - r * cols;
    d[i] = (r < rows_src) ? f2bf(s[r * cols + c]) : (u16)0;
  }
}

// ---------------------------------------------------------------------------
// MFMA GEMM (m97 recipe): C[M,N] = A[M,K] * W[N,K]^T, bf16 in, fp32 acc.
// 128x128 block tile, BK=32, 256 threads = 4 waves (2x2), 64x64 per wave.
// ---------------------------------------------------------------------------
template <int OUT_F32>
__global__ __launch_bounds__(256) void gemm_bt_mfma(
    const u16* __restrict__ A, int lda,
    const u16* __restrict__ W, int ldw,
    void* __restrict__ Cv, int ldc, int K) {
  __shared__ u16 Asm[128 * 32];
  __shared__ u16 Bsm[128 * 32];
  int tid = threadIdx.x;
  int lane = tid & 63, w = tid >> 6;
  int wm = (w >> 1) * 64, wn = (w & 1) * 64;
  int bm = blockIdx.y * 128, bn = blockIdx.x * 128;

  floatx4 acc[4][4];
#pragma unroll
  for (int i = 0; i < 4; i++)
#pragma unroll
    for (int j = 0; j < 4; j++) acc[i][j] = (floatx4){0.f, 0.f, 0.f, 0.f};

  int sr = lane >> 2;          // staging row within 16-row chunk
  int sc = (lane & 3) * 8;     // staging bf16 col offset (16B/lane)
  int fr = lane & 15;          // fragment m/n within 16
  int fq = (lane >> 4) * 8;    // fragment k offset within 32

  for (int k0 = 0; k0 < K; k0 += 32) {
#pragma unroll
    for (int c = 0; c < 2; c++) {
      int row = 32 * w + 16 * c + sr;
      gld_lds16(A + (size_t)(bm + row) * lda + k0 + sc, &Asm[(32 * w + 16 * c) * 32]);
      gld_lds16(W + (size_t)(bn + row) * ldw + k0 + sc, &Bsm[(32 * w + 16 * c) * 32]);
    }
    __syncthreads();
    short8 af[4], bfr[4];
#pragma unroll
    for (int i = 0; i < 4; i++)
      af[i] = *(const short8*)&Asm[(wm + i * 16 + fr) * 32 + fq];
#pragma unroll
    for (int j = 0; j < 4; j++)
      bfr[j] = *(const short8*)&Bsm[(wn + j * 16 + fr) * 32 + fq];
#pragma unroll
    for (int i = 0; i < 4; i++)
#pragma unroll
      for (int j = 0; j < 4; j++)
        acc[i][j] = __builtin_amdgcn_mfma_f32_16x16x32_bf16(af[i], bfr[j], acc[i][j], 0, 0, 0);
    __syncthreads();
  }

  int cr = (lane >> 4) * 4, cc = lane & 15;
#pragma unroll
  for (int i = 0; i < 4; i++)
#pragma unroll
    for (int j = 0; j < 4; j++) {
      int col = bn + wn + j * 16 + cc;
#pragma unroll
      for (int r = 0; r < 4; r++) {
        size_t row = (size_t)(bm + wm + i * 16 + cr + r);
        if (OUT_F32) ((float*)Cv)[row * ldc + col] = acc[i][j][r];
        else         ((u16*)Cv)[row * ldc + col] = f2bf(acc[i][j][r]);
      }
    }
}

// ---------------------------------------------------------------------------
// RMSNorm (bf16 data, fp32 norm weights, fp32 math)
// ---------------------------------------------------------------------------
__global__ __launch_bounds__(256) void rmsnorm_k(
    const u16* __restrict__ in, const float* __restrict__ w,
    u16* __restrict__ out, int width, int stride) {
  int row = blockIdx.x;
  const u16* p = in + (size_t)row * stride;
  u16* o = out + (size_t)row * stride;
  float ss = 0.f;
  for (int i = threadIdx.x; i < width; i += 256) { float v = bf2f(p[i]); ss += v * v; }
  for (int off = 32; off > 0; off >>= 1) ss += __shfl_down(ss, off);
  __shared__ float red[4];
  if ((threadIdx.x & 63) == 0) red[threadIdx.x >> 6] = ss;
  __syncthreads();
  float inv = rsqrtf((red[0] + red[1] + red[2] + red[3]) / (float)width + 1e-6f);
  for (int i = threadIdx.x; i < width; i += 256)
    o[i] = f2bf(bf2f(p[i]) * inv * w[i]);
}

// ---------------------------------------------------------------------------
// RoPE in-place (bf16 data, fp32 cos/sin). grid=(tokens, heads), block=32.
// ---------------------------------------------------------------------------
__global__ void rope_k(u16* __restrict__ base, int row_stride, int head_stride,
                       int head_off, const float* __restrict__ cosb,
                       const float* __restrict__ sinb, int S) {
  int t = blockIdx.x, h = blockIdx.y, i = threadIdx.x;  // i in [0,32)
  int pos = t % S;
  u16* p = base + (size_t)t * row_stride + h * head_stride + head_off;
  float c1 = cosb[pos * 64 + i];
  float c2 = cosb[pos * 64 + i + 32];
  float s1 = sinb[pos * 64 + i];
  float s2 = sinb[pos * 64 + i + 32];
  float x1 = bf2f(p[i]), x2 = bf2f(p[i + 32]);
  p[i]      = f2bf(x1 * c1 - x2 * s1);
  p[i + 32] = f2bf(x2 * c2 + x1 * s2);
}

// ---------------------------------------------------------------------------
// V transpose: kvb V-part [tok][h*256+128+vd] -> vt[((b*16+h)*128+vd)*S + tok]
// Block: 64 tokens of one (b,h). 256 threads.
// ---------------------------------------------------------------------------
__global__ __launch_bounds__(256) void vtrans_k(
    const u16* __restrict__ kvb, u16* __restrict__ vt, int S) {
  int tb = blockIdx.x, h = blockIdx.y, b = blockIdx.z;
  __shared__ __align__(16) u16 Ts[64][136];   // pad keeps store-phase reads ~conflict-free
  int tid = threadIdx.x;
#pragma unroll
  for (int it = 0; it < 4; it++) {
    int e = tid + 256 * it;        // chunk id, 16 chunks (of 8 shorts) per token row
    int tok = e >> 4, c = e & 15;
    short8 v = *(const short8*)(kvb + (size_t)(b * S + tb * 64 + tok) * 4096 + h * 256 + 128 + c * 8);
    *(short8*)&Ts[tok][c * 8] = v;
  }
  __syncthreads();
  int vd = tid >> 1, half = (tid & 1) * 32;
  u16 tmp[32];
#pragma unroll
  for (int j = 0; j < 32; j++) tmp[j] = Ts[half + j][vd];
  u16* dst = vt + ((size_t)((b * 16 + h) * 128) + vd) * S + tb * 64 + half;
#pragma unroll
  for (int c = 0; c < 4; c++)
    *(short8*)(dst + c * 8) = *(short8*)&tmp[c * 8];
}

// ---------------------------------------------------------------------------
// MFMA flash attention. Block = (64 q-rows, head h, batch b); 4 waves.
// qf : [B*S, 3072]  (16 heads * 192, rope applied)
// kvb: [B*S, 4096]  (16 heads * (k_nope 128 | v 128))
// kpe: [B*S, 640]   (cols 512..575 = roped k_pe, shared by heads)
// vt : [B*16*128, S] (V transposed, K-major)
// at : [B*S, 2048]
// ---------------------------------------------------------------------------
#define AT_BK 64
__global__ __launch_bounds__(256) void attn_mfma(
    const u16* __restrict__ qf, const u16* __restrict__ kvb,
    const u16* __restrict__ kpe, const u16* __restrict__ vt,
    u16* __restrict__ at, int S) {
  int qt = blockIdx.x, h = blockIdx.y, b = blockIdx.z;
  int q0 = qt * 64;
  int tid = threadIdx.x, lane = tid & 63, w = tid >> 6;
  int fr = lane & 15, fq = lane >> 4;   // fragment row / k-quad

  __shared__ __align__(16) u16 Ksn[AT_BK * 128];  // [key][128] k_nope
  __shared__ __align__(16) u16 Ksp[AT_BK * 64];   // [key][64]  k_pe
  __shared__ __align__(16) u16 Vts[128 * AT_BK];  // [vd][key]
  __shared__ __align__(16) u16 Ps[64 * AT_BK];    // [qrow][key] probs bf16

  // Q fragments direct from global: A[m=fr][k=fq*8+j], 6 k-steps of 32
  short8 qfrag[6];
  {
    const u16* qrow = qf + (size_t)(b * S + q0 + w * 16 + fr) * 3072 + h * 192 + fq * 8;
#pragma unroll
    for (int ks = 0; ks < 6; ks++) qfrag[ks] = *(const short8*)(qrow + ks * 32);
  }

  floatx4 acc_o[8];
#pragma unroll
  for (int j = 0; j < 8; j++) acc_o[j] = (floatx4){0.f, 0.f, 0.f, 0.f};
  float m_r[4], l_r[4];
#pragma unroll
  for (int r = 0; r < 4; r++) { m_r[r] = -3e38f; l_r[r] = 0.f; }

  const float scale = 0.07216878364870323f;  // 192^-0.5

  for (int kt = 0; kt <= qt; kt++) {
    int k0 = kt * AT_BK;
    size_t tokbase = (size_t)(b * S + k0);
    // ---- stage K (nope+pe) and V^T; each wave stages its share ----
#pragma unroll
    for (int c = 0; c < 4; c++) {  // Ksn: wave w rows w*16..+15, 4 rows/call
      int row = w * 16 + c * 4 + (lane >> 4);
      gld_lds16(kvb + (tokbase + row) * 4096 + h * 256 + (lane & 15) * 8,
                &Ksn[(w * 16 + c * 4) * 128]);
    }
#pragma unroll
    for (int c = 0; c < 2; c++) {  // Ksp: 8 rows/call
      int row = w * 16 + c * 8 + (lane >> 3);
      gld_lds16(kpe + (tokbase + row) * 640 + 512 + (lane & 7) * 8,
                &Ksp[(w * 16 + c * 8) * 64]);
    }
#pragma unroll
    for (int c = 0; c < 4; c++) {  // Vts: wave w vd-rows w*32..+31, 8 rows/call
      int vd = w * 32 + c * 8 + (lane >> 3);
      gld_lds16(vt + ((size_t)((b * 16 + h) * 128) + vd) * S + k0 + (lane & 7) * 8,
                &Vts[(w * 32 + c * 8) * 64]);
    }
    __syncthreads();

    // ---- S = Q K^T for wave's 16 rows x 64 keys ----
    floatx4 accs[4];
#pragma unroll
    for (int nt = 0; nt < 4; nt++) accs[nt] = (floatx4){0.f, 0.f, 0.f, 0.f};
#pragma unroll
    for (int nt = 0; nt < 4; nt++) {
#pragma unroll
      for (int ks = 0; ks < 4; ks++) {
        short8 bf = *(const short8*)&Ksn[(nt * 16 + fr) * 128 + ks * 32 + fq * 8];
        accs[nt] = __builtin_amdgcn_mfma_f32_16x16x32_bf16(qfrag[ks], bf, accs[nt], 0, 0, 0);
      }
#pragma unroll
      for (int ks = 0; ks < 2; ks++) {
        short8 bf = *(const short8*)&Ksp[(nt * 16 + fr) * 64 + ks * 32 + fq * 8];
        accs[nt] = __builtin_amdgcn_mfma_f32_16x16x32_bf16(qfrag[4 + ks], bf, accs[nt], 0, 0, 0);
      }
    }

    // ---- scale + causal mask (diagonal tile only) ----
    bool diag = (kt == qt);
#pragma unroll
    for (int nt = 0; nt < 4; nt++)
#pragma unroll
      for (int r = 0; r < 4; r++) {
        float s = accs[nt][r] * scale;
        if (diag) {
          int col = nt * 16 + fr;        // key within tile
          int row = fq * 4 + r;          // query within m-tile
          if (k0 + col > q0 + w * 16 + row) s = -3e38f;
        }
        accs[nt][r] = s;
      }

    // ---- in-register online softmax (rows live in fixed lanes) ----
    float alpha[4], rsum[4];
#pragma unroll
    for (int r = 0; r < 4; r++) {
      float mx = fmaxf(fmaxf(accs[0][r], accs[1][r]), fmaxf(accs[2][r], accs[3][r]));
      mx = fmaxf(mx, __shfl_xor(mx, 1));
      mx = fmaxf(mx, __shfl_xor(mx, 2));
      mx = fmaxf(mx, __shfl_xor(mx, 4));
      mx = fmaxf(mx, __shfl_xor(mx, 8));
      float mnew = fmaxf(m_r[r], mx);
      alpha[r] = __expf(m_r[r] - mnew);
      m_r[r] = mnew;
      rsum[r] = 0.f;
    }
#pragma unroll
    for (int nt = 0; nt < 4; nt++)
#pragma unroll
      for (int r = 0; r < 4; r++) {
        float p = __expf(accs[nt][r] - m_r[r]);
        rsum[r] += p;
        Ps[(w * 16 + fq * 4 + r) * AT_BK + nt * 16 + fr] = f2bf(p);
      }
#pragma unroll
    for (int r = 0; r < 4; r++) {
      float sm = rsum[r];
      sm += __shfl_xor(sm, 1);
      sm += __shfl_xor(sm, 2);
      sm += __shfl_xor(sm, 4);
      sm += __shfl_xor(sm, 8);
      l_r[r] = l_r[r] * alpha[r] + sm;
    }
    __syncthreads();   // Ps visible to PV reads

    // ---- O = O*alpha + P V ----
#pragma unroll
    for (int j = 0; j < 8; j++)
#pragma unroll
      for (int r = 0; r < 4; r++) acc_o[j][r] *= alpha[r];
    short8 pf0 = *(const short8*)&Ps[(w * 16 + fr) * AT_BK + fq * 8];
    short8 pf1 = *(const short8*)&Ps[(w * 16 + fr) * AT_BK + 32 + fq * 8];
#pragma unroll
    for (int j = 0; j < 8; j++) {
      short8 v0 = *(const short8*)&Vts[(j * 16 + fr) * AT_BK + fq * 8];
      short8 v1 = *(const short8*)&Vts[(j * 16 + fr) * AT_BK + 32 + fq * 8];
      acc_o[j] = __builtin_amdgcn_mfma_f32_16x16x32_bf16(pf0, v0, acc_o[j], 0, 0, 0);
      acc_o[j] = __builtin_amdgcn_mfma_f32_16x16x32_bf16(pf1, v1, acc_o[j], 0, 0, 0);
    }
    __syncthreads();   // before next tile's staging overwrites LDS
  }

  // ---- epilogue: divide by l, store ----
  float inv_l[4];
#pragma unroll
  for (int r = 0; r < 4; r++) inv_l[r] = 1.f / l_r[r];
#pragma unroll
  for (int j = 0; j < 8; j++)
#pragma unroll
    for (int r = 0; r < 4; r++) {
      size_t row = (size_t)(b * S + q0 + w * 16 + fq * 4 + r);
      at[row * 2048 + h * 128 + j * 16 + fr] = f2bf(acc_o[j][r] * inv_l[r]);
    }
}

// ---------------------------------------------------------------------------
extern "C" void kernel_launch(void* const* d_in, const int* in_sizes, int n_in,
                              void* d_out, int out_size, void* d_ws, size_t ws_size,
                              hipStream_t stream) {
  (void)in_sizes; (void)n_in; (void)out_size; (void)ws_size;
  const float* x     = (const float*)d_in[0];
  const float* cosb  = (const float*)d_in[1];
  const float* sinb  = (const float*)d_in[2];
  const float* wq_a  = (const float*)d_in[3];
  const float* qnw   = (const float*)d_in[4];
  const float* wq_b  = (const float*)d_in[5];
  const float* wkv_a = (const float*)d_in[6];
  const float* kvnw  = (const float*)d_in[7];
  const float* wkv_b = (const float*)d_in[8];
  const float* wo    = (const float*)d_in[9];
  float* out = (float*)d_out;
  const int B = 2, S = 2048, T = B * S;

  char* wsb = (char*)d_ws;
  size_t off = 0;
  u16* xb   = (u16*)(wsb + off); off += (size_t)T * 2048 * 2;
  u16* wqab = (u16*)(wsb + off); off += (size_t)1536 * 2048 * 2;
  u16* wqbb = (u16*)(wsb + off); off += (size_t)3072 * 1536 * 2;
  u16* wkab = (u16*)(wsb + off); off += (size_t)640 * 2048 * 2;   // padded 576->640
  u16* wkbb = (u16*)(wsb + off); off += (size_t)4096 * 512 * 2;
  u16* wob  = (u16*)(wsb + off); off += (size_t)2048 * 2048 * 2;
  u16* qa   = (u16*)(wsb + off); off += (size_t)T * 1536 * 2;
  u16* kvp  = (u16*)(wsb + off); off += (size_t)T * 640 * 2;
  u16* qf   = (u16*)(wsb + off); off += (size_t)T * 3072 * 2;
  u16* kvb  = (u16*)(wsb + off); off += (size_t)T * 4096 * 2;
  u16* at   = (u16*)(wsb + off); off += (size_t)T * 2048 * 2;
  u16* vt   = xb;   // reuse: xb is dead after GEMMs 1-2; vt is same size (T*2048)

  auto conv = [&](const float* s, u16* d, long n) {
    f2b_k<<<(int)((n / 4 + 255) / 256), 256, 0, stream>>>(s, d, n);
  };
  conv(x, xb, (long)T * 2048);
  conv(wq_a, wqab, (long)1536 * 2048);
  conv(wq_b, wqbb, (long)3072 * 1536);
  f2b_pad_k<<<(int)(((long)640 * 2048 + 255) / 256), 256, 0, stream>>>(wkv_a, wkab, 576, 2048, 640);
  conv(wkv_b, wkbb, (long)4096 * 512);
  conv(wo, wob, (long)2048 * 2048);

  // 1) qa = xb @ wq_a^T  [T,1536]
  gemm_bt_mfma<0><<<dim3(1536 / 128, T / 128), 256, 0, stream>>>(xb, 2048, wqab, 2048, qa, 1536, 2048);
  // 2) kvp = xb @ wkv_a^T [T,640]
  gemm_bt_mfma<0><<<dim3(640 / 128, T / 128), 256, 0, stream>>>(xb, 2048, wkab, 2048, kvp, 640, 2048);
  // 3) rmsnorm(qa)
  rmsnorm_k<<<T, 256, 0, stream>>>(qa, qnw, qa, 1536, 1536);
  // 4) rmsnorm(kv_c); rope(k_pe)
  rmsnorm_k<<<T, 256, 0, stream>>>(kvp, kvnw, kvp, 512, 640);
  rope_k<<<dim3(T, 1), 32, 0, stream>>>(kvp, 640, 0, 512, cosb, sinb, S);
  // 5) qf = qa @ wq_b^T [T,3072]; rope q_pe
  gemm_bt_mfma<0><<<dim3(3072 / 128, T / 128), 256, 0, stream>>>(qa, 1536, wqbb, 1536, qf, 3072, 1536);
  rope_k<<<dim3(T, 16), 32, 0, stream>>>(qf, 3072, 192, 128, cosb, sinb, S);
  // 6) kvb = kv_norm @ wkv_b^T [T,4096]
  gemm_bt_mfma<0><<<dim3(4096 / 128, T / 128), 256, 0, stream>>>(kvp, 640, wkbb, 512, kvb, 4096, 512);
  // 6.5) V transpose (vt overlays dead xb)
  vtrans_k<<<dim3(S / 64, 16, B), 256, 0, stream>>>(kvb, vt, S);
  // 7) MFMA flash attention -> at [T,2048]
  attn_mfma<<<dim3(S / 64, 16, B), 256, 0, stream>>>(qf, kvb, kvp, vt, at, S);
  // 8) out = at @ wo^T [T,2048] fp32
  gemm_bt_mfma<1><<<dim3(2048 / 128, T / 128), 256, 0, stream>>>(at, 2048, wob, 2048, out, 2048, 2048);
}

// Round 5
// 630.426 us; speedup vs baseline: 8.7144x; 1.1792x over previous
//
#include <hip/hip_runtime.h>

typedef unsigned short u16;
typedef __attribute__((ext_vector_type(8))) short short8;   // 8 bf16 = 4 VGPRs
typedef __attribute__((ext_vector_type(4))) float floatx4;

__device__ __forceinline__ float bf2f(u16 u) {
  union { unsigned int i; float f; } v; v.i = ((unsigned int)u) << 16; return v.f;
}
__device__ __forceinline__ u16 f2bf(float f) {
  union { float f; unsigned int i; } v; v.f = f;
  unsigned int u = v.i;
  u += 0x7fffu + ((u >> 16) & 1u);   // RNE
  return (u16)(u >> 16);
}

__device__ __forceinline__ void gld_lds16(const void* g, void* l) {
  __builtin_amdgcn_global_load_lds(
      (const __attribute__((address_space(1))) unsigned int*)g,
      (__attribute__((address_space(3))) unsigned int*)l, 16, 0, 0);
}

// ---------------------------------------------------------------------------
// fp32 -> bf16 repack (inputs are bf16-quantized fp32, so this is lossless)
// ---------------------------------------------------------------------------
__global__ __launch_bounds__(256) void f2b_k(const float* __restrict__ s,
                                             u16* __restrict__ d, long n) {
  long i = ((long)blockIdx.x * 256 + threadIdx.x) * 4;
  if (i + 3 < n) {
    float4 v = *(const float4*)(s + i);
    d[i + 0] = f2bf(v.x); d[i + 1] = f2bf(v.y);
    d[i + 2] = f2bf(v.z); d[i + 3] = f2bf(v.w);
  } else {
    for (; i < n; i++) d[i] = f2bf(s[i]);
  }
}

__global__ __launch_bounds__(256) void f2b_pad_k(const float* __restrict__ s,
                                                 u16* __restrict__ d,
                                                 int rows_src, int cols, int rows_dst) {
  long i = (long)blockIdx.x * 256 + threadIdx.x;
  long total = (long)rows_dst * cols;
  if (i < total) {
    long r = i / cols, c = i - r * cols;
    d[i] = (r < rows_src) ? f2bf(s[r * cols + c]) : (u16)0;
  }
}

// ---------------------------------------------------------------------------
// MFMA GEMM (m97 recipe): C[M,N] = A[M,K] * W[N,K]^T, bf16 in, fp32 acc.
// 128x128 block tile, BK=32, 256 threads = 4 waves (2x2), 64x64 per wave.
// ---------------------------------------------------------------------------
template <int OUT_F32>
__global__ __launch_bounds__(256) void gemm_bt_mfma(
    const u16* __restrict__ A, int lda,
    const u16* __restrict__ W, int ldw,
    void* __restrict__ Cv, int ldc, int K) {
  __shared__ u16 Asm[128 * 32];
  __shared__ u16 Bsm[128 * 32];
  int tid = threadIdx.x;
  int lane = tid & 63, w = tid >> 6;
  int wm = (w >> 1) * 64, wn = (w & 1) * 64;
  int bm = blockIdx.y * 128, bn = blockIdx.x * 128;

  floatx4 acc[4][4];
#pragma unroll
  for (int i = 0; i < 4; i++)
#pragma unroll
    for (int j = 0; j < 4; j++) acc[i][j] = (floatx4){0.f, 0.f, 0.f, 0.f};

  int sr = lane >> 2;          // staging row within 16-row chunk
  int sc = (lane & 3) * 8;     // staging bf16 col offset (16B/lane)
  int fr = lane & 15;          // fragment m/n within 16
  int fq = (lane >> 4) * 8;    // fragment k offset within 32

  for (int k0 = 0; k0 < K; k0 += 32) {
#pragma unroll
    for (int c = 0; c < 2; c++) {
      int row = 32 * w + 16 * c + sr;
      gld_lds16(A + (size_t)(bm + row) * lda + k0 + sc, &Asm[(32 * w + 16 * c) * 32]);
      gld_lds16(W + (size_t)(bn + row) * ldw + k0 + sc, &Bsm[(32 * w + 16 * c) * 32]);
    }
    __syncthreads();
    short8 af[4], bfr[4];
#pragma unroll
    for (int i = 0; i < 4; i++)
      af[i] = *(const short8*)&Asm[(wm + i * 16 + fr) * 32 + fq];
#pragma unroll
    for (int j = 0; j < 4; j++)
      bfr[j] = *(const short8*)&Bsm[(wn + j * 16 + fr) * 32 + fq];
#pragma unroll
    for (int i = 0; i < 4; i++)
#pragma unroll
      for (int j = 0; j < 4; j++)
        acc[i][j] = __builtin_amdgcn_mfma_f32_16x16x32_bf16(af[i], bfr[j], acc[i][j], 0, 0, 0);
    __syncthreads();
  }

  int cr = (lane >> 4) * 4, cc = lane & 15;
#pragma unroll
  for (int i = 0; i < 4; i++)
#pragma unroll
    for (int j = 0; j < 4; j++) {
      int col = bn + wn + j * 16 + cc;
#pragma unroll
      for (int r = 0; r < 4; r++) {
        size_t row = (size_t)(bm + wm + i * 16 + cr + r);
        if (OUT_F32) ((float*)Cv)[row * ldc + col] = acc[i][j][r];
        else         ((u16*)Cv)[row * ldc + col] = f2bf(acc[i][j][r]);
      }
    }
}

// ---------------------------------------------------------------------------
// RMSNorm (bf16 data, fp32 norm weights, fp32 math)
// ---------------------------------------------------------------------------
__global__ __launch_bounds__(256) void rmsnorm_k(
    const u16* __restrict__ in, const float* __restrict__ w,
    u16* __restrict__ out, int width, int stride) {
  int row = blockIdx.x;
  const u16* p = in + (size_t)row * stride;
  u16* o = out + (size_t)row * stride;
  float ss = 0.f;
  for (int i = threadIdx.x; i < width; i += 256) { float v = bf2f(p[i]); ss += v * v; }
  for (int off = 32; off > 0; off >>= 1) ss += __shfl_down(ss, off);
  __shared__ float red[4];
  if ((threadIdx.x & 63) == 0) red[threadIdx.x >> 6] = ss;
  __syncthreads();
  float inv = rsqrtf((red[0] + red[1] + red[2] + red[3]) / (float)width + 1e-6f);
  for (int i = threadIdx.x; i < width; i += 256)
    o[i] = f2bf(bf2f(p[i]) * inv * w[i]);
}

// ---------------------------------------------------------------------------
// RoPE in-place (bf16 data, fp32 cos/sin). grid=(tokens, heads), block=32.
// ---------------------------------------------------------------------------
__global__ void rope_k(u16* __restrict__ base, int row_stride, int head_stride,
                       int head_off, const float* __restrict__ cosb,
                       const float* __restrict__ sinb, int S) {
  int t = blockIdx.x, h = blockIdx.y, i = threadIdx.x;  // i in [0,32)
  int pos = t % S;
  u16* p = base + (size_t)t * row_stride + h * head_stride + head_off;
  float c1 = cosb[pos * 64 + i];
  float c2 = cosb[pos * 64 + i + 32];
  float s1 = sinb[pos * 64 + i];
  float s2 = sinb[pos * 64 + i + 32];
  float x1 = bf2f(p[i]), x2 = bf2f(p[i + 32]);
  p[i]      = f2bf(x1 * c1 - x2 * s1);
  p[i + 32] = f2bf(x2 * c2 + x1 * s2);
}

// ---------------------------------------------------------------------------
// V transpose: kvb V-part [tok][h*256+128+vd] -> vt[((b*16+h)*128+vd)*S + tok]
// ---------------------------------------------------------------------------
__global__ __launch_bounds__(256) void vtrans_k(
    const u16* __restrict__ kvb, u16* __restrict__ vt, int S) {
  int tb = blockIdx.x, h = blockIdx.y, b = blockIdx.z;
  __shared__ __align__(16) u16 Ts[64][136];
  int tid = threadIdx.x;
#pragma unroll
  for (int it = 0; it < 4; it++) {
    int e = tid + 256 * it;
    int tok = e >> 4, c = e & 15;
    short8 v = *(const short8*)(kvb + (size_t)(b * S + tb * 64 + tok) * 4096 + h * 256 + 128 + c * 8);
    *(short8*)&Ts[tok][c * 8] = v;
  }
  __syncthreads();
  int vd = tid >> 1, half = (tid & 1) * 32;
  u16 tmp[32];
#pragma unroll
  for (int j = 0; j < 32; j++) tmp[j] = Ts[half + j][vd];
  u16* dst = vt + ((size_t)((b * 16 + h) * 128) + vd) * S + tb * 64 + half;
#pragma unroll
  for (int c = 0; c < 4; c++)
    *(short8*)(dst + c * 8) = *(short8*)&tmp[c * 8];
}

// ---------------------------------------------------------------------------
// MFMA flash attention, XOR bank swizzle on all LDS arrays.
// Chunk (16B) index is XOR'd with (row & 7) both at staging (by permuting the
// per-lane GLOBAL fetch; LDS dest of global_load_lds stays lane*16) and at
// ds_read. Makes every 8-lane/128B phase hit 8 distinct bank groups.
// ---------------------------------------------------------------------------
#define AT_BK 64
__global__ __launch_bounds__(256) void attn_mfma(
    const u16* __restrict__ qf, const u16* __restrict__ kvb,
    const u16* __restrict__ kpe, const u16* __restrict__ vt,
    u16* __restrict__ at, int S) {
  int qt = blockIdx.x, h = blockIdx.y, b = blockIdx.z;
  int q0 = qt * 64;
  int tid = threadIdx.x, lane = tid & 63, w = tid >> 6;
  int fr = lane & 15, fq = lane >> 4;   // fragment row / k-quad
  int fs = fr & 7;                      // swizzle key for reads

  __shared__ __align__(16) u16 Ksn[AT_BK * 128];  // [key][16 chunks]
  __shared__ __align__(16) u16 Ksp[AT_BK * 64];   // [key][8 chunks]
  __shared__ __align__(16) u16 Vts[128 * AT_BK];  // [vd][8 chunks]
  __shared__ __align__(16) u16 Ps[64 * AT_BK];    // [qrow][8 chunks]

  // Q fragments direct from global: A[m=fr][k=fq*8+j], 6 k-steps of 32
  short8 qfrag[6];
  {
    const u16* qrow = qf + (size_t)(b * S + q0 + w * 16 + fr) * 3072 + h * 192 + fq * 8;
#pragma unroll
    for (int ks = 0; ks < 6; ks++) qfrag[ks] = *(const short8*)(qrow + ks * 32);
  }

  floatx4 acc_o[8];
#pragma unroll
  for (int j = 0; j < 8; j++) acc_o[j] = (floatx4){0.f, 0.f, 0.f, 0.f};
  float m_r[4], l_r[4];
#pragma unroll
  for (int r = 0; r < 4; r++) { m_r[r] = -3e38f; l_r[r] = 0.f; }

  const float scale = 0.07216878364870323f;  // 192^-0.5

  for (int kt = 0; kt <= qt; kt++) {
    int k0 = kt * AT_BK;
    size_t tokbase = (size_t)(b * S + k0);
    // ---- stage K (nope+pe) and V^T with swizzled per-lane global chunk ----
#pragma unroll
    for (int c = 0; c < 4; c++) {  // Ksn: 4 rows/call, 16 chunks/row
      int row = w * 16 + c * 4 + (lane >> 4);
      int cg = (lane & 15) ^ (row & 7);
      gld_lds16(kvb + (tokbase + row) * 4096 + h * 256 + cg * 8,
                &Ksn[(w * 16 + c * 4) * 128]);
    }
#pragma unroll
    for (int c = 0; c < 2; c++) {  // Ksp: 8 rows/call, 8 chunks/row
      int row = w * 16 + c * 8 + (lane >> 3);
      int cg = (lane & 7) ^ (row & 7);
      gld_lds16(kpe + (tokbase + row) * 640 + 512 + cg * 8,
                &Ksp[(w * 16 + c * 8) * 64]);
    }
#pragma unroll
    for (int c = 0; c < 4; c++) {  // Vts: 8 vd-rows/call, 8 chunks/row
      int vd = w * 32 + c * 8 + (lane >> 3);
      int cg = (lane & 7) ^ (vd & 7);
      gld_lds16(vt + ((size_t)((b * 16 + h) * 128) + vd) * S + k0 + cg * 8,
                &Vts[(w * 32 + c * 8) * 64]);
    }
    __syncthreads();

    // ---- S = Q K^T for wave's 16 rows x 64 keys ----
    floatx4 accs[4];
#pragma unroll
    for (int nt = 0; nt < 4; nt++) accs[nt] = (floatx4){0.f, 0.f, 0.f, 0.f};
#pragma unroll
    for (int nt = 0; nt < 4; nt++) {
#pragma unroll
      for (int ks = 0; ks < 4; ks++) {
        short8 bf = *(const short8*)&Ksn[(nt * 16 + fr) * 128 + ((ks * 4 + fq) ^ fs) * 8];
        accs[nt] = __builtin_amdgcn_mfma_f32_16x16x32_bf16(qfrag[ks], bf, accs[nt], 0, 0, 0);
      }
#pragma unroll
      for (int ks = 0; ks < 2; ks++) {
        short8 bf = *(const short8*)&Ksp[(nt * 16 + fr) * 64 + ((ks * 4 + fq) ^ fs) * 8];
        accs[nt] = __builtin_amdgcn_mfma_f32_16x16x32_bf16(qfrag[4 + ks], bf, accs[nt], 0, 0, 0);
      }
    }

    // ---- scale + causal mask (diagonal tile only) ----
    bool diag = (kt == qt);
#pragma unroll
    for (int nt = 0; nt < 4; nt++)
#pragma unroll
      for (int r = 0; r < 4; r++) {
        float s = accs[nt][r] * scale;
        if (diag) {
          int col = nt * 16 + fr;
          int row = fq * 4 + r;
          if (k0 + col > q0 + w * 16 + row) s = -3e38f;
        }
        accs[nt][r] = s;
      }

    // ---- in-register online softmax ----
    float alpha[4], rsum[4];
#pragma unroll
    for (int r = 0; r < 4; r++) {
      float mx = fmaxf(fmaxf(accs[0][r], accs[1][r]), fmaxf(accs[2][r], accs[3][r]));
      mx = fmaxf(mx, __shfl_xor(mx, 1));
      mx = fmaxf(mx, __shfl_xor(mx, 2));
      mx = fmaxf(mx, __shfl_xor(mx, 4));
      mx = fmaxf(mx, __shfl_xor(mx, 8));
      float mnew = fmaxf(m_r[r], mx);
      alpha[r] = __expf(m_r[r] - mnew);
      m_r[r] = mnew;
      rsum[r] = 0.f;
    }
#pragma unroll
    for (int nt = 0; nt < 4; nt++)
#pragma unroll
      for (int r = 0; r < 4; r++) {
        float p = __expf(accs[nt][r] - m_r[r]);
        rsum[r] += p;
        int row_p = w * 16 + fq * 4 + r;
        int col = nt * 16 + fr;
        Ps[row_p * 64 + (((col >> 3) ^ (row_p & 7)) * 8) + (col & 7)] = f2bf(p);
      }
#pragma unroll
    for (int r = 0; r < 4; r++) {
      float sm = rsum[r];
      sm += __shfl_xor(sm, 1);
      sm += __shfl_xor(sm, 2);
      sm += __shfl_xor(sm, 4);
      sm += __shfl_xor(sm, 8);
      l_r[r] = l_r[r] * alpha[r] + sm;
    }
    __syncthreads();   // Ps visible to PV reads

    // ---- O = O*alpha + P V ----
#pragma unroll
    for (int j = 0; j < 8; j++)
#pragma unroll
      for (int r = 0; r < 4; r++) acc_o[j][r] *= alpha[r];
    short8 pf0 = *(const short8*)&Ps[(w * 16 + fr) * 64 + (fq ^ fs) * 8];
    short8 pf1 = *(const short8*)&Ps[(w * 16 + fr) * 64 + ((4 + fq) ^ fs) * 8];
#pragma unroll
    for (int j = 0; j < 8; j++) {
      short8 v0 = *(const short8*)&Vts[(j * 16 + fr) * 64 + (fq ^ fs) * 8];
      short8 v1 = *(const short8*)&Vts[(j * 16 + fr) * 64 + ((4 + fq) ^ fs) * 8];
      acc_o[j] = __builtin_amdgcn_mfma_f32_16x16x32_bf16(pf0, v0, acc_o[j], 0, 0, 0);
      acc_o[j] = __builtin_amdgcn_mfma_f32_16x16x32_bf16(pf1, v1, acc_o[j], 0, 0, 0);
    }
    __syncthreads();   // before next tile's staging overwrites LDS
  }

  // ---- epilogue ----
  float inv_l[4];
#pragma unroll
  for (int r = 0; r < 4; r++) inv_l[r] = 1.f / l_r[r];
#pragma unroll
  for (int j = 0; j < 8; j++)
#pragma unroll
    for (int r = 0; r < 4; r++) {
      size_t row = (size_t)(b * S + q0 + w * 16 + fq * 4 + r);
      at[row * 2048 + h * 128 + j * 16 + fr] = f2bf(acc_o[j][r] * inv_l[r]);
    }
}

// ---------------------------------------------------------------------------
extern "C" void kernel_launch(void* const* d_in, const int* in_sizes, int n_in,
                              void* d_out, int out_size, void* d_ws, size_t ws_size,
                              hipStream_t stream) {
  (void)in_sizes; (void)n_in; (void)out_size; (void)ws_size;
  const float* x     = (const float*)d_in[0];
  const float* cosb  = (const float*)d_in[1];
  const float* sinb  = (const float*)d_in[2];
  const float* wq_a  = (const float*)d_in[3];
  const float* qnw   = (const float*)d_in[4];
  const float* wq_b  = (const float*)d_in[5];
  const float* wkv_a = (const float*)d_in[6];
  const float* kvnw  = (const float*)d_in[7];
  const float* wkv_b = (const float*)d_in[8];
  const float* wo    = (const float*)d_in[9];
  float* out = (float*)d_out;
  const int B = 2, S = 2048, T = B * S;

  char* wsb = (char*)d_ws;
  size_t off = 0;
  u16* xb   = (u16*)(wsb + off); off += (size_t)T * 2048 * 2;
  u16* wqab = (u16*)(wsb + off); off += (size_t)1536 * 2048 * 2;
  u16* wqbb = (u16*)(wsb + off); off += (size_t)3072 * 1536 * 2;
  u16* wkab = (u16*)(wsb + off); off += (size_t)640 * 2048 * 2;   // padded 576->640
  u16* wkbb = (u16*)(wsb + off); off += (size_t)4096 * 512 * 2;
  u16* wob  = (u16*)(wsb + off); off += (size_t)2048 * 2048 * 2;
  u16* qa   = (u16*)(wsb + off); off += (size_t)T * 1536 * 2;
  u16* kvp  = (u16*)(wsb + off); off += (size_t)T * 640 * 2;
  u16* qf   = (u16*)(wsb + off); off += (size_t)T * 3072 * 2;
  u16* kvb  = (u16*)(wsb + off); off += (size_t)T * 4096 * 2;
  u16* at   = (u16*)(wsb + off); off += (size_t)T * 2048 * 2;
  u16* vt   = xb;   // reuse: xb dead after GEMMs 1-2; same size (T*2048)

  auto conv = [&](const float* s, u16* d, long n) {
    f2b_k<<<(int)((n / 4 + 255) / 256), 256, 0, stream>>>(s, d, n);
  };
  conv(x, xb, (long)T * 2048);
  conv(wq_a, wqab, (long)1536 * 2048);
  conv(wq_b, wqbb, (long)3072 * 1536);
  f2b_pad_k<<<(int)(((long)640 * 2048 + 255) / 256), 256, 0, stream>>>(wkv_a, wkab, 576, 2048, 640);
  conv(wkv_b, wkbb, (long)4096 * 512);
  conv(wo, wob, (long)2048 * 2048);

  // 1) qa = xb @ wq_a^T  [T,1536]
  gemm_bt_mfma<0><<<dim3(1536 / 128, T / 128), 256, 0, stream>>>(xb, 2048, wqab, 2048, qa, 1536, 2048);
  // 2) kvp = xb @ wkv_a^T [T,640]
  gemm_bt_mfma<0><<<dim3(640 / 128, T / 128), 256, 0, stream>>>(xb, 2048, wkab, 2048, kvp, 640, 2048);
  // 3) rmsnorm(qa)
  rmsnorm_k<<<T, 256, 0, stream>>>(qa, qnw, qa, 1536, 1536);
  // 4) rmsnorm(kv_c); rope(k_pe)
  rmsnorm_k<<<T, 256, 0, stream>>>(kvp, kvnw, kvp, 512, 640);
  rope_k<<<dim3(T, 1), 32, 0, stream>>>(kvp, 640, 0, 512, cosb, sinb, S);
  // 5) qf = qa @ wq_b^T [T,3072]; rope q_pe
  gemm_bt_mfma<0><<<dim3(3072 / 128, T / 128), 256, 0, stream>>>(qa, 1536, wqbb, 1536, qf, 3072, 1536);
  rope_k<<<dim3(T, 16), 32, 0, stream>>>(qf, 3072, 192, 128, cosb, sinb, S);
  // 6) kvb = kv_norm @ wkv_b^T [T,4096]
  gemm_bt_mfma<0><<<dim3(4096 / 128, T / 128), 256, 0, stream>>>(kvp, 640, wkbb, 512, kvb, 4096, 512);
  // 6.5) V transpose (vt overlays dead xb)
  vtrans_k<<<dim3(S / 64, 16, B), 256, 0, stream>>>(kvb, vt, S);
  // 7) MFMA flash attention -> at [T,2048]
  attn_mfma<<<dim3(S / 64, 16, B), 256, 0, stream>>>(qf, kvb, kvp, vt, at, S);
  // 8) out = at @ wo^T [T,2048] fp32
  gemm_bt_mfma<1><<<dim3(2048 / 128, T / 128), 256, 0, stream>>>(at, 2048, wob, 2048, out, 2048, 2048);
}

// Round 6
// 516.882 us; speedup vs baseline: 10.6287x; 1.2197x over previous
//
#include <hip/hip_runtime.h>

typedef unsigned short u16;
typedef __attribute__((ext_vector_type(8))) short short8;   // 8 bf16 = 4 VGPRs
typedef __attribute__((ext_vector_type(4))) float floatx4;

__device__ __forceinline__ float bf2f(u16 u) {
  union { unsigned int i; float f; } v; v.i = ((unsigned int)u) << 16; return v.f;
}
__device__ __forceinline__ u16 f2bf(float f) {
  union { float f; unsigned int i; } v; v.f = f;
  unsigned int u = v.i;
  u += 0x7fffu + ((u >> 16) & 1u);   // RNE
  return (u16)(u >> 16);
}

__device__ __forceinline__ void gld_lds16(const void* g, void* l) {
  __builtin_amdgcn_global_load_lds(
      (const __attribute__((address_space(1))) unsigned int*)g,
      (__attribute__((address_space(3))) unsigned int*)l, 16, 0, 0);
}

// ---------------------------------------------------------------------------
// fp32 -> bf16 repack (inputs are bf16-quantized fp32, so this is lossless)
// ---------------------------------------------------------------------------
__global__ __launch_bounds__(256) void f2b_k(const float* __restrict__ s,
                                             u16* __restrict__ d, long n) {
  long i = ((long)blockIdx.x * 256 + threadIdx.x) * 4;
  if (i + 3 < n) {
    float4 v = *(const float4*)(s + i);
    d[i + 0] = f2bf(v.x); d[i + 1] = f2bf(v.y);
    d[i + 2] = f2bf(v.z); d[i + 3] = f2bf(v.w);
  } else {
    for (; i < n; i++) d[i] = f2bf(s[i]);
  }
}

// Concatenated weight repack: rows [0,r1) from s1, [r1,r1+r2) from s2, else 0.
__global__ __launch_bounds__(256) void wcat_k(const float* __restrict__ s1, int r1,
                                              const float* __restrict__ s2, int r2,
                                              u16* __restrict__ d, int cols, int rows_dst) {
  long i = (long)blockIdx.x * 256 + threadIdx.x;
  long total = (long)rows_dst * cols;
  if (i < total) {
    long r = i / cols, c = i - r * cols;
    float v = 0.f;
    if (r < r1) v = s1[r * cols + c];
    else if (r < r1 + r2) v = s2[(r - r1) * cols + c];
    d[i] = f2bf(v);
  }
}

// ---------------------------------------------------------------------------
// MFMA GEMM (m97 recipe): C[M,N] = A[M,K] * W[N,K]^T, bf16 in, fp32 acc.
// 128x128 block tile, BK=32, 256 threads = 4 waves (2x2), 64x64 per wave.
// ---------------------------------------------------------------------------
template <int OUT_F32>
__global__ __launch_bounds__(256) void gemm_bt_mfma(
    const u16* __restrict__ A, int lda,
    const u16* __restrict__ W, int ldw,
    void* __restrict__ Cv, int ldc, int K) {
  __shared__ u16 Asm[128 * 32];
  __shared__ u16 Bsm[128 * 32];
  int tid = threadIdx.x;
  int lane = tid & 63, w = tid >> 6;
  int wm = (w >> 1) * 64, wn = (w & 1) * 64;
  int bm = blockIdx.y * 128, bn = blockIdx.x * 128;

  floatx4 acc[4][4];
#pragma unroll
  for (int i = 0; i < 4; i++)
#pragma unroll
    for (int j = 0; j < 4; j++) acc[i][j] = (floatx4){0.f, 0.f, 0.f, 0.f};

  int sr = lane >> 2;          // staging row within 16-row chunk
  int sc = (lane & 3) * 8;     // staging bf16 col offset (16B/lane)
  int fr = lane & 15;          // fragment m/n within 16
  int fq = (lane >> 4) * 8;    // fragment k offset within 32

  for (int k0 = 0; k0 < K; k0 += 32) {
#pragma unroll
    for (int c = 0; c < 2; c++) {
      int row = 32 * w + 16 * c + sr;
      gld_lds16(A + (size_t)(bm + row) * lda + k0 + sc, &Asm[(32 * w + 16 * c) * 32]);
      gld_lds16(W + (size_t)(bn + row) * ldw + k0 + sc, &Bsm[(32 * w + 16 * c) * 32]);
    }
    __syncthreads();
    short8 af[4], bfr[4];
#pragma unroll
    for (int i = 0; i < 4; i++)
      af[i] = *(const short8*)&Asm[(wm + i * 16 + fr) * 32 + fq];
#pragma unroll
    for (int j = 0; j < 4; j++)
      bfr[j] = *(const short8*)&Bsm[(wn + j * 16 + fr) * 32 + fq];
#pragma unroll
    for (int i = 0; i < 4; i++)
#pragma unroll
      for (int j = 0; j < 4; j++)
        acc[i][j] = __builtin_amdgcn_mfma_f32_16x16x32_bf16(af[i], bfr[j], acc[i][j], 0, 0, 0);
    __syncthreads();
  }

  int cr = (lane >> 4) * 4, cc = lane & 15;
#pragma unroll
  for (int i = 0; i < 4; i++)
#pragma unroll
    for (int j = 0; j < 4; j++) {
      int col = bn + wn + j * 16 + cc;
#pragma unroll
      for (int r = 0; r < 4; r++) {
        size_t row = (size_t)(bm + wm + i * 16 + cr + r);
        if (OUT_F32) ((float*)Cv)[row * ldc + col] = acc[i][j][r];
        else         ((u16*)Cv)[row * ldc + col] = f2bf(acc[i][j][r]);
      }
    }
}

// ---------------------------------------------------------------------------
// RMSNorm (bf16 data, fp32 norm weights, fp32 math), strided rows, in-place ok
// ---------------------------------------------------------------------------
__global__ __launch_bounds__(256) void rmsnorm_k(
    const u16* __restrict__ in, const float* __restrict__ w,
    u16* __restrict__ out, int width, int stride) {
  int row = blockIdx.x;
  const u16* p = in + (size_t)row * stride;
  u16* o = out + (size_t)row * stride;
  float ss = 0.f;
  for (int i = threadIdx.x; i < width; i += 256) { float v = bf2f(p[i]); ss += v * v; }
  for (int off = 32; off > 0; off >>= 1) ss += __shfl_down(ss, off);
  __shared__ float red[4];
  if ((threadIdx.x & 63) == 0) red[threadIdx.x >> 6] = ss;
  __syncthreads();
  float inv = rsqrtf((red[0] + red[1] + red[2] + red[3]) / (float)width + 1e-6f);
  for (int i = threadIdx.x; i < width; i += 256)
    o[i] = f2bf(bf2f(p[i]) * inv * w[i]);
}

// ---------------------------------------------------------------------------
// RoPE in-place (bf16 data, fp32 cos/sin). grid=(tokens, heads), block=32.
// ---------------------------------------------------------------------------
__global__ void rope_k(u16* __restrict__ base, int row_stride, int head_stride,
                       int head_off, const float* __restrict__ cosb,
                       const float* __restrict__ sinb, int S) {
  int t = blockIdx.x, h = blockIdx.y, i = threadIdx.x;  // i in [0,32)
  int pos = t % S;
  u16* p = base + (size_t)t * row_stride + h * head_stride + head_off;
  float c1 = cosb[pos * 64 + i];
  float c2 = cosb[pos * 64 + i + 32];
  float s1 = sinb[pos * 64 + i];
  float s2 = sinb[pos * 64 + i + 32];
  float x1 = bf2f(p[i]), x2 = bf2f(p[i + 32]);
  p[i]      = f2bf(x1 * c1 - x2 * s1);
  p[i + 32] = f2bf(x2 * c2 + x1 * s2);
}

// ---------------------------------------------------------------------------
// V transpose: kvb V-part [tok][h*256+128+vd] -> vt[((b*16+h)*128+vd)*S + tok]
// ---------------------------------------------------------------------------
__global__ __launch_bounds__(256) void vtrans_k(
    const u16* __restrict__ kvb, u16* __restrict__ vt, int S) {
  int tb = blockIdx.x, h = blockIdx.y, b = blockIdx.z;
  __shared__ __align__(16) u16 Ts[64][136];
  int tid = threadIdx.x;
#pragma unroll
  for (int it = 0; it < 4; it++) {
    int e = tid + 256 * it;
    int tok = e >> 4, c = e & 15;
    short8 v = *(const short8*)(kvb + (size_t)(b * S + tb * 64 + tok) * 4096 + h * 256 + 128 + c * 8);
    *(short8*)&Ts[tok][c * 8] = v;
  }
  __syncthreads();
  int vd = tid >> 1, half = (tid & 1) * 32;
  u16 tmp[32];
#pragma unroll
  for (int j = 0; j < 32; j++) tmp[j] = Ts[half + j][vd];
  u16* dst = vt + ((size_t)((b * 16 + h) * 128) + vd) * S + tb * 64 + half;
#pragma unroll
  for (int c = 0; c < 4; c++)
    *(short8*)(dst + c * 8) = *(short8*)&tmp[c * 8];
}

// ---------------------------------------------------------------------------
// MFMA flash attention, XOR bank swizzle, paired q-tiles for load balance.
// Block pair = blockIdx.x in [0, S/128): handles qt = pair and qt = NT-1-pair
// sequentially -> every block does exactly NT+1 key-tile iterations.
// ---------------------------------------------------------------------------
#define AT_BK 64
__global__ __launch_bounds__(256) void attn_mfma(
    const u16* __restrict__ qf, const u16* __restrict__ kvb,
    const u16* __restrict__ kpe, int kpe_stride, const u16* __restrict__ vt,
    u16* __restrict__ at, int S) {
  int pair = blockIdx.x, h = blockIdx.y, b = blockIdx.z;
  int NT = S / AT_BK;
  int tid = threadIdx.x, lane = tid & 63, w = tid >> 6;
  int fr = lane & 15, fq = lane >> 4;   // fragment row / k-quad
  int fs = fr & 7;                      // swizzle key for reads

  __shared__ __align__(16) u16 Ksn[AT_BK * 128];  // [key][16 chunks]
  __shared__ __align__(16) u16 Ksp[AT_BK * 64];   // [key][8 chunks]
  __shared__ __align__(16) u16 Vts[128 * AT_BK];  // [vd][8 chunks]
  __shared__ __align__(16) u16 Ps[64 * AT_BK];    // [qrow][8 chunks]

  const float scale = 0.07216878364870323f;  // 192^-0.5

  for (int p = 0; p < 2; p++) {
    int qt = p ? (NT - 1 - pair) : pair;
    int q0 = qt * 64;

    // Q fragments direct from global: A[m=fr][k=fq*8+j], 6 k-steps of 32
    short8 qfrag[6];
    {
      const u16* qrow = qf + (size_t)(b * S + q0 + w * 16 + fr) * 3072 + h * 192 + fq * 8;
#pragma unroll
      for (int ks = 0; ks < 6; ks++) qfrag[ks] = *(const short8*)(qrow + ks * 32);
    }

    floatx4 acc_o[8];
#pragma unroll
    for (int j = 0; j < 8; j++) acc_o[j] = (floatx4){0.f, 0.f, 0.f, 0.f};
    float m_r[4], l_r[4];
#pragma unroll
    for (int r = 0; r < 4; r++) { m_r[r] = -3e38f; l_r[r] = 0.f; }

    for (int kt = 0; kt <= qt; kt++) {
      int k0 = kt * AT_BK;
      size_t tokbase = (size_t)(b * S + k0);
      // ---- stage K (nope+pe) and V^T with swizzled per-lane global chunk ----
#pragma unroll
      for (int c = 0; c < 4; c++) {  // Ksn: 4 rows/call, 16 chunks/row
        int row = w * 16 + c * 4 + (lane >> 4);
        int cg = (lane & 15) ^ (row & 7);
        gld_lds16(kvb + (tokbase + row) * 4096 + h * 256 + cg * 8,
                  &Ksn[(w * 16 + c * 4) * 128]);
      }
#pragma unroll
      for (int c = 0; c < 2; c++) {  // Ksp: 8 rows/call, 8 chunks/row
        int row = w * 16 + c * 8 + (lane >> 3);
        int cg = (lane & 7) ^ (row & 7);
        gld_lds16(kpe + (tokbase + row) * kpe_stride + cg * 8,
                  &Ksp[(w * 16 + c * 8) * 64]);
      }
#pragma unroll
      for (int c = 0; c < 4; c++) {  // Vts: 8 vd-rows/call, 8 chunks/row
        int vd = w * 32 + c * 8 + (lane >> 3);
        int cg = (lane & 7) ^ (vd & 7);
        gld_lds16(vt + ((size_t)((b * 16 + h) * 128) + vd) * S + k0 + cg * 8,
                  &Vts[(w * 32 + c * 8) * 64]);
      }
      __syncthreads();

      // ---- S = Q K^T for wave's 16 rows x 64 keys ----
      floatx4 accs[4];
#pragma unroll
      for (int nt = 0; nt < 4; nt++) accs[nt] = (floatx4){0.f, 0.f, 0.f, 0.f};
#pragma unroll
      for (int nt = 0; nt < 4; nt++) {
#pragma unroll
        for (int ks = 0; ks < 4; ks++) {
          short8 bf = *(const short8*)&Ksn[(nt * 16 + fr) * 128 + ((ks * 4 + fq) ^ fs) * 8];
          accs[nt] = __builtin_amdgcn_mfma_f32_16x16x32_bf16(qfrag[ks], bf, accs[nt], 0, 0, 0);
        }
#pragma unroll
        for (int ks = 0; ks < 2; ks++) {
          short8 bf = *(const short8*)&Ksp[(nt * 16 + fr) * 64 + ((ks * 4 + fq) ^ fs) * 8];
          accs[nt] = __builtin_amdgcn_mfma_f32_16x16x32_bf16(qfrag[4 + ks], bf, accs[nt], 0, 0, 0);
        }
      }

      // ---- scale + causal mask (diagonal tile only) ----
      bool diag = (kt == qt);
#pragma unroll
      for (int nt = 0; nt < 4; nt++)
#pragma unroll
        for (int r = 0; r < 4; r++) {
          float s = accs[nt][r] * scale;
          if (diag) {
            int col = nt * 16 + fr;
            int row = fq * 4 + r;
            if (k0 + col > q0 + w * 16 + row) s = -3e38f;
          }
          accs[nt][r] = s;
        }

      // ---- in-register online softmax ----
      float alpha[4], rsum[4];
#pragma unroll
      for (int r = 0; r < 4; r++) {
        float mx = fmaxf(fmaxf(accs[0][r], accs[1][r]), fmaxf(accs[2][r], accs[3][r]));
        mx = fmaxf(mx, __shfl_xor(mx, 1));
        mx = fmaxf(mx, __shfl_xor(mx, 2));
        mx = fmaxf(mx, __shfl_xor(mx, 4));
        mx = fmaxf(mx, __shfl_xor(mx, 8));
        float mnew = fmaxf(m_r[r], mx);
        alpha[r] = __expf(m_r[r] - mnew);
        m_r[r] = mnew;
        rsum[r] = 0.f;
      }
#pragma unroll
      for (int nt = 0; nt < 4; nt++)
#pragma unroll
        for (int r = 0; r < 4; r++) {
          float pv = __expf(accs[nt][r] - m_r[r]);
          rsum[r] += pv;
          int row_p = w * 16 + fq * 4 + r;
          int col = nt * 16 + fr;
          Ps[row_p * 64 + (((col >> 3) ^ (row_p & 7)) * 8) + (col & 7)] = f2bf(pv);
        }
#pragma unroll
      for (int r = 0; r < 4; r++) {
        float sm = rsum[r];
        sm += __shfl_xor(sm, 1);
        sm += __shfl_xor(sm, 2);
        sm += __shfl_xor(sm, 4);
        sm += __shfl_xor(sm, 8);
        l_r[r] = l_r[r] * alpha[r] + sm;
      }
      __syncthreads();   // Ps visible to PV reads

      // ---- O = O*alpha + P V ----
#pragma unroll
      for (int j = 0; j < 8; j++)
#pragma unroll
        for (int r = 0; r < 4; r++) acc_o[j][r] *= alpha[r];
      short8 pf0 = *(const short8*)&Ps[(w * 16 + fr) * 64 + (fq ^ fs) * 8];
      short8 pf1 = *(const short8*)&Ps[(w * 16 + fr) * 64 + ((4 + fq) ^ fs) * 8];
#pragma unroll
      for (int j = 0; j < 8; j++) {
        short8 v0 = *(const short8*)&Vts[(j * 16 + fr) * 64 + (fq ^ fs) * 8];
        short8 v1 = *(const short8*)&Vts[(j * 16 + fr) * 64 + ((4 + fq) ^ fs) * 8];
        acc_o[j] = __builtin_amdgcn_mfma_f32_16x16x32_bf16(pf0, v0, acc_o[j], 0, 0, 0);
        acc_o[j] = __builtin_amdgcn_mfma_f32_16x16x32_bf16(pf1, v1, acc_o[j], 0, 0, 0);
      }
      __syncthreads();   // before next tile's staging overwrites LDS
    }

    // ---- epilogue for this q-tile ----
    float inv_l[4];
#pragma unroll
    for (int r = 0; r < 4; r++) inv_l[r] = 1.f / l_r[r];
#pragma unroll
    for (int j = 0; j < 8; j++)
#pragma unroll
      for (int r = 0; r < 4; r++) {
        size_t row = (size_t)(b * S + q0 + w * 16 + fq * 4 + r);
        at[row * 2048 + h * 128 + j * 16 + fr] = f2bf(acc_o[j][r] * inv_l[r]);
      }
  }
}

// ---------------------------------------------------------------------------
extern "C" void kernel_launch(void* const* d_in, const int* in_sizes, int n_in,
                              void* d_out, int out_size, void* d_ws, size_t ws_size,
                              hipStream_t stream) {
  (void)in_sizes; (void)n_in; (void)out_size; (void)ws_size;
  const float* x     = (const float*)d_in[0];
  const float* cosb  = (const float*)d_in[1];
  const float* sinb  = (const float*)d_in[2];
  const float* wq_a  = (const float*)d_in[3];
  const float* qnw   = (const float*)d_in[4];
  const float* wq_b  = (const float*)d_in[5];
  const float* wkv_a = (const float*)d_in[6];
  const float* kvnw  = (const float*)d_in[7];
  const float* wkv_b = (const float*)d_in[8];
  const float* wo    = (const float*)d_in[9];
  float* out = (float*)d_out;
  const int B = 2, S = 2048, T = B * S;

  char* wsb = (char*)d_ws;
  size_t off = 0;
  u16* xb   = (u16*)(wsb + off); off += (size_t)T * 2048 * 2;
  u16* wcat = (u16*)(wsb + off); off += (size_t)2176 * 2048 * 2;  // wq_a|wkv_a|pad
  u16* wqbb = (u16*)(wsb + off); off += (size_t)3072 * 1536 * 2;
  u16* wkbb = (u16*)(wsb + off); off += (size_t)4096 * 512 * 2;
  u16* wob  = (u16*)(wsb + off); off += (size_t)2048 * 2048 * 2;
  u16* qkv  = (u16*)(wsb + off); off += (size_t)T * 2176 * 2;     // qa|kv|kpe
  u16* qf   = (u16*)(wsb + off); off += (size_t)T * 3072 * 2;
  u16* kvb  = (u16*)(wsb + off); off += (size_t)T * 4096 * 2;
  u16* at   = (u16*)(wsb + off); off += (size_t)T * 2048 * 2;
  u16* vt   = xb;   // reuse: xb dead after GEMM 1; same size (T*2048)

  auto conv = [&](const float* s, u16* d, long n) {
    f2b_k<<<(int)((n / 4 + 255) / 256), 256, 0, stream>>>(s, d, n);
  };
  conv(x, xb, (long)T * 2048);
  wcat_k<<<(int)(((long)2176 * 2048 + 255) / 256), 256, 0, stream>>>(
      wq_a, 1536, wkv_a, 576, wcat, 2048, 2176);
  conv(wq_b, wqbb, (long)3072 * 1536);
  conv(wkv_b, wkbb, (long)4096 * 512);
  conv(wo, wob, (long)2048 * 2048);

  // 1) qkv = xb @ [wq_a;wkv_a]^T   [T,2176]  (qa | kv | kpe | pad)
  gemm_bt_mfma<0><<<dim3(2176 / 128, T / 128), 256, 0, stream>>>(xb, 2048, wcat, 2048, qkv, 2176, 2048);
  // 2) rmsnorm(qa cols 0..1535)
  rmsnorm_k<<<T, 256, 0, stream>>>(qkv, qnw, qkv, 1536, 2176);
  // 3) rmsnorm(kv cols 1536..2047); rope(kpe cols 2048..2111)
  rmsnorm_k<<<T, 256, 0, stream>>>(qkv + 1536, kvnw, qkv + 1536, 512, 2176);
  rope_k<<<dim3(T, 1), 32, 0, stream>>>(qkv, 2176, 0, 2048, cosb, sinb, S);
  // 4) qf = qa @ wq_b^T [T,3072]; rope q_pe
  gemm_bt_mfma<0><<<dim3(3072 / 128, T / 128), 256, 0, stream>>>(qkv, 2176, wqbb, 1536, qf, 3072, 1536);
  rope_k<<<dim3(T, 16), 32, 0, stream>>>(qf, 3072, 192, 128, cosb, sinb, S);
  // 5) kvb = kv_norm @ wkv_b^T [T,4096]
  gemm_bt_mfma<0><<<dim3(4096 / 128, T / 128), 256, 0, stream>>>(qkv + 1536, 2176, wkbb, 512, kvb, 4096, 512);
  // 6) V transpose (vt overlays dead xb)
  vtrans_k<<<dim3(S / 64, 16, B), 256, 0, stream>>>(kvb, vt, S);
  // 7) MFMA flash attention (paired q-tiles) -> at [T,2048]
  attn_mfma<<<dim3(S / 128, 16, B), 256, 0, stream>>>(qf, kvb, qkv + 2048, 2176, vt, at, S);
  // 8) out = at @ wo^T [T,2048] fp32
  gemm_bt_mfma<1><<<dim3(2048 / 128, T / 128), 256, 0, stream>>>(at, 2048, wob, 2048, out, 2048, 2048);
}

// Round 7
// 481.373 us; speedup vs baseline: 11.4128x; 1.0738x over previous
//
#include <hip/hip_runtime.h>

typedef unsigned short u16;
typedef __attribute__((ext_vector_type(8))) short short8;   // 8 bf16 = 4 VGPRs
typedef __attribute__((ext_vector_type(4))) float floatx4;

__device__ __forceinline__ float bf2f(u16 u) {
  union { unsigned int i; float f; } v; v.i = ((unsigned int)u) << 16; return v.f;
}
__device__ __forceinline__ u16 f2bf(float f) {
  union { float f; unsigned int i; } v; v.f = f;
  unsigned int u = v.i;
  u += 0x7fffu + ((u >> 16) & 1u);   // RNE
  return (u16)(u >> 16);
}

__device__ __forceinline__ void gld_lds16(const void* g, void* l) {
  __builtin_amdgcn_global_load_lds(
      (const __attribute__((address_space(1))) unsigned int*)g,
      (__attribute__((address_space(3))) unsigned int*)l, 16, 0, 0);
}

// ---------------------------------------------------------------------------
// One-shot repack: blockIdx.y selects region.
//  0: x      [4096,2048] -> xb
//  1: wcat   rows 0..1535 wq_a, 1536..2111 wkv_a, 2112..2175 zero  (cols 2048)
//  2: wq_b   [3072,1536] -> wqbb
//  3: wkv_b  [4096,512]  -> wkbb
//  4: wo     [2048,2048] -> wob
// ---------------------------------------------------------------------------
__global__ __launch_bounds__(256) void repack_all_k(
    const float* __restrict__ x, const float* __restrict__ wqa,
    const float* __restrict__ wkva, const float* __restrict__ wqb,
    const float* __restrict__ wkvb, const float* __restrict__ wo,
    u16* __restrict__ xb, u16* __restrict__ wcat, u16* __restrict__ wqbb,
    u16* __restrict__ wkbb, u16* __restrict__ wob) {
  long i = ((long)blockIdx.x * 256 + threadIdx.x) * 4;
  int region = blockIdx.y;
  const float* s = nullptr; u16* d = nullptr; long n = 0;
  switch (region) {
    case 0: s = x;    d = xb;   n = 4096L * 2048; break;
    case 1: s = nullptr; d = wcat; n = 2176L * 2048; break;
    case 2: s = wqb;  d = wqbb; n = 3072L * 1536; break;
    case 3: s = wkvb; d = wkbb; n = 4096L * 512;  break;
    case 4: s = wo;   d = wob;  n = 2048L * 2048; break;
  }
  if (i >= n) return;
  float4 v;
  if (region == 1) {  // concatenated + padded (chunks never cross rows: 2048%4==0)
    long r = i >> 11, c = i & 2047;
    if (r < 1536)      v = *(const float4*)(wqa + r * 2048 + c);
    else if (r < 2112) v = *(const float4*)(wkva + (r - 1536) * 2048 + c);
    else               v = (float4){0.f, 0.f, 0.f, 0.f};
  } else {
    v = *(const float4*)(s + i);
  }
  d[i + 0] = f2bf(v.x); d[i + 1] = f2bf(v.y);
  d[i + 2] = f2bf(v.z); d[i + 3] = f2bf(v.w);
}

// ---------------------------------------------------------------------------
// MFMA GEMM tile body (m97 recipe): C[128,128] tile of A[M,K] * W[N,K]^T.
// ---------------------------------------------------------------------------
template <int OUT_F32>
__device__ __forceinline__ void gemm_tile(
    const u16* __restrict__ A, int lda, const u16* __restrict__ W, int ldw,
    void* __restrict__ Cv, int ldc, int K, int bm, int bn,
    u16* Asm, u16* Bsm) {
  int tid = threadIdx.x;
  int lane = tid & 63, w = tid >> 6;
  int wm = (w >> 1) * 64, wn = (w & 1) * 64;

  floatx4 acc[4][4];
#pragma unroll
  for (int i = 0; i < 4; i++)
#pragma unroll
    for (int j = 0; j < 4; j++) acc[i][j] = (floatx4){0.f, 0.f, 0.f, 0.f};

  int sr = lane >> 2;          // staging row within 16-row chunk
  int sc = (lane & 3) * 8;     // staging bf16 col offset (16B/lane)
  int fr = lane & 15;          // fragment m/n within 16
  int fq = (lane >> 4) * 8;    // fragment k offset within 32

  for (int k0 = 0; k0 < K; k0 += 32) {
#pragma unroll
    for (int c = 0; c < 2; c++) {
      int row = 32 * w + 16 * c + sr;
      gld_lds16(A + (size_t)(bm + row) * lda + k0 + sc, &Asm[(32 * w + 16 * c) * 32]);
      gld_lds16(W + (size_t)(bn + row) * ldw + k0 + sc, &Bsm[(32 * w + 16 * c) * 32]);
    }
    __syncthreads();
    short8 af[4], bfr[4];
#pragma unroll
    for (int i = 0; i < 4; i++)
      af[i] = *(const short8*)&Asm[(wm + i * 16 + fr) * 32 + fq];
#pragma unroll
    for (int j = 0; j < 4; j++)
      bfr[j] = *(const short8*)&Bsm[(wn + j * 16 + fr) * 32 + fq];
#pragma unroll
    for (int i = 0; i < 4; i++)
#pragma unroll
      for (int j = 0; j < 4; j++)
        acc[i][j] = __builtin_amdgcn_mfma_f32_16x16x32_bf16(af[i], bfr[j], acc[i][j], 0, 0, 0);
    __syncthreads();
  }

  int cr = (lane >> 4) * 4, cc = lane & 15;
#pragma unroll
  for (int i = 0; i < 4; i++)
#pragma unroll
    for (int j = 0; j < 4; j++) {
      int col = bn + wn + j * 16 + cc;
#pragma unroll
      for (int r = 0; r < 4; r++) {
        size_t row = (size_t)(bm + wm + i * 16 + cr + r);
        if (OUT_F32) ((float*)Cv)[row * ldc + col] = acc[i][j][r];
        else         ((u16*)Cv)[row * ldc + col] = f2bf(acc[i][j][r]);
      }
    }
}

template <int OUT_F32>
__global__ __launch_bounds__(256) void gemm_bt_mfma(
    const u16* __restrict__ A, int lda,
    const u16* __restrict__ W, int ldw,
    void* __restrict__ Cv, int ldc, int K) {
  __shared__ u16 Asm[128 * 32];
  __shared__ u16 Bsm[128 * 32];
  gemm_tile<OUT_F32>(A, lda, W, ldw, Cv, ldc, K, blockIdx.y * 128, blockIdx.x * 128, Asm, Bsm);
}

// Two GEMMs sharing one dispatch: blockIdx.x < nt1 -> GEMM1, else GEMM2.
__global__ __launch_bounds__(256) void gemm_dual_mfma(
    const u16* __restrict__ A1, int lda1, const u16* __restrict__ W1, int ldw1,
    u16* __restrict__ C1, int ldc1, int K1, int nt1,
    const u16* __restrict__ A2, int lda2, const u16* __restrict__ W2, int ldw2,
    u16* __restrict__ C2, int ldc2, int K2) {
  __shared__ u16 Asm[128 * 32];
  __shared__ u16 Bsm[128 * 32];
  int bx = blockIdx.x;
  if (bx < nt1)
    gemm_tile<0>(A1, lda1, W1, ldw1, C1, ldc1, K1, blockIdx.y * 128, bx * 128, Asm, Bsm);
  else
    gemm_tile<0>(A2, lda2, W2, ldw2, C2, ldc2, K2, blockIdx.y * 128, (bx - nt1) * 128, Asm, Bsm);
}

// ---------------------------------------------------------------------------
// Fused per-row: rmsnorm(qa cols 0..1535), rmsnorm(kv cols 1536..2047),
// rope(kpe cols 2048..2111). One block per row of qkv [T, 2176].
// ---------------------------------------------------------------------------
__global__ __launch_bounds__(256) void normrope_k(
    u16* __restrict__ qkv, const float* __restrict__ qnw,
    const float* __restrict__ kvnw, const float* __restrict__ cosb,
    const float* __restrict__ sinb, int S) {
  int row = blockIdx.x, tid = threadIdx.x;
  u16* p = qkv + (size_t)row * 2176;
  float s1 = 0.f, s2 = 0.f;
#pragma unroll
  for (int it = 0; it < 6; it++) { float v = bf2f(p[tid + 256 * it]); s1 += v * v; }
#pragma unroll
  for (int it = 0; it < 2; it++) { float v = bf2f(p[1536 + tid + 256 * it]); s2 += v * v; }
  for (int off = 32; off > 0; off >>= 1) {
    s1 += __shfl_down(s1, off);
    s2 += __shfl_down(s2, off);
  }
  __shared__ float red1[4], red2[4];
  if ((tid & 63) == 0) { red1[tid >> 6] = s1; red2[tid >> 6] = s2; }
  __syncthreads();
  float inv1 = rsqrtf((red1[0] + red1[1] + red1[2] + red1[3]) / 1536.f + 1e-6f);
  float inv2 = rsqrtf((red2[0] + red2[1] + red2[2] + red2[3]) / 512.f + 1e-6f);
#pragma unroll
  for (int it = 0; it < 6; it++) {
    int i = tid + 256 * it;
    p[i] = f2bf(bf2f(p[i]) * inv1 * qnw[i]);
  }
#pragma unroll
  for (int it = 0; it < 2; it++) {
    int i = tid + 256 * it;
    p[1536 + i] = f2bf(bf2f(p[1536 + i]) * inv2 * kvnw[i]);
  }
  if (tid < 32) {
    int pos = row % S;
    float c1 = cosb[pos * 64 + tid];
    float c2 = cosb[pos * 64 + tid + 32];
    float sn1 = sinb[pos * 64 + tid];
    float sn2 = sinb[pos * 64 + tid + 32];
    float x1 = bf2f(p[2048 + tid]), x2 = bf2f(p[2048 + tid + 32]);
    p[2048 + tid]      = f2bf(x1 * c1 - x2 * sn1);
    p[2048 + tid + 32] = f2bf(x2 * c2 + x1 * sn2);
  }
}

// ---------------------------------------------------------------------------
// RoPE in-place for q heads. grid=(tokens, heads), block=32.
// ---------------------------------------------------------------------------
__global__ void rope_k(u16* __restrict__ base, int row_stride, int head_stride,
                       int head_off, const float* __restrict__ cosb,
                       const float* __restrict__ sinb, int S) {
  int t = blockIdx.x, h = blockIdx.y, i = threadIdx.x;  // i in [0,32)
  int pos = t % S;
  u16* p = base + (size_t)t * row_stride + h * head_stride + head_off;
  float c1 = cosb[pos * 64 + i];
  float c2 = cosb[pos * 64 + i + 32];
  float s1 = sinb[pos * 64 + i];
  float s2 = sinb[pos * 64 + i + 32];
  float x1 = bf2f(p[i]), x2 = bf2f(p[i + 32]);
  p[i]      = f2bf(x1 * c1 - x2 * s1);
  p[i + 32] = f2bf(x2 * c2 + x1 * s2);
}

// ---------------------------------------------------------------------------
// V transpose: kvb V-part [tok][h*256+128+vd] -> vt[((b*16+h)*128+vd)*S + tok]
// ---------------------------------------------------------------------------
__global__ __launch_bounds__(256) void vtrans_k(
    const u16* __restrict__ kvb, u16* __restrict__ vt, int S) {
  int tb = blockIdx.x, h = blockIdx.y, b = blockIdx.z;
  __shared__ __align__(16) u16 Ts[64][136];
  int tid = threadIdx.x;
#pragma unroll
  for (int it = 0; it < 4; it++) {
    int e = tid + 256 * it;
    int tok = e >> 4, c = e & 15;
    short8 v = *(const short8*)(kvb + (size_t)(b * S + tb * 64 + tok) * 4096 + h * 256 + 128 + c * 8);
    *(short8*)&Ts[tok][c * 8] = v;
  }
  __syncthreads();
  int vd = tid >> 1, half = (tid & 1) * 32;
  u16 tmp[32];
#pragma unroll
  for (int j = 0; j < 32; j++) tmp[j] = Ts[half + j][vd];
  u16* dst = vt + ((size_t)((b * 16 + h) * 128) + vd) * S + tb * 64 + half;
#pragma unroll
  for (int c = 0; c < 4; c++)
    *(short8*)(dst + c * 8) = *(short8*)&tmp[c * 8];
}

// ---------------------------------------------------------------------------
// MFMA flash attention. 1D grid, id = pair*32 + (h + 16*b)  =>  the 16
// pair-blocks of a given (b,h) share id%8, i.e. one XCD under round-robin
// dispatch -> that head's K/V stays L2-resident. Paired q-tiles balance work.
// ---------------------------------------------------------------------------
#define AT_BK 64
__global__ __launch_bounds__(256) void attn_mfma(
    const u16* __restrict__ qf, const u16* __restrict__ kvb,
    const u16* __restrict__ kpe, int kpe_stride, const u16* __restrict__ vt,
    u16* __restrict__ at, int S) {
  int id = blockIdx.x;
  int pair = id >> 5, hb = id & 31;
  int h = hb & 15, b = hb >> 4;
  int NT = S / AT_BK;
  int tid = threadIdx.x, lane = tid & 63, w = tid >> 6;
  int fr = lane & 15, fq = lane >> 4;   // fragment row / k-quad
  int fs = fr & 7;                      // swizzle key for reads

  __shared__ __align__(16) u16 Ksn[AT_BK * 128];  // [key][16 chunks]
  __shared__ __align__(16) u16 Ksp[AT_BK * 64];   // [key][8 chunks]
  __shared__ __align__(16) u16 Vts[128 * AT_BK];  // [vd][8 chunks]
  __shared__ __align__(16) u16 Ps[64 * AT_BK];    // [qrow][8 chunks]

  const float scale = 0.07216878364870323f;  // 192^-0.5

  for (int p = 0; p < 2; p++) {
    int qt = p ? (NT - 1 - pair) : pair;
    int q0 = qt * 64;

    // Q fragments direct from global: A[m=fr][k=fq*8+j], 6 k-steps of 32
    short8 qfrag[6];
    {
      const u16* qrow = qf + (size_t)(b * S + q0 + w * 16 + fr) * 3072 + h * 192 + fq * 8;
#pragma unroll
      for (int ks = 0; ks < 6; ks++) qfrag[ks] = *(const short8*)(qrow + ks * 32);
    }

    floatx4 acc_o[8];
#pragma unroll
    for (int j = 0; j < 8; j++) acc_o[j] = (floatx4){0.f, 0.f, 0.f, 0.f};
    float m_r[4], l_r[4];   // l_r: per-lane PARTIAL sums (reduced in epilogue)
#pragma unroll
    for (int r = 0; r < 4; r++) { m_r[r] = -3e38f; l_r[r] = 0.f; }

    for (int kt = 0; kt <= qt; kt++) {
      int k0 = kt * AT_BK;
      size_t tokbase = (size_t)(b * S + k0);
      // ---- stage K (nope+pe) and V^T with swizzled per-lane global chunk ----
#pragma unroll
      for (int c = 0; c < 4; c++) {  // Ksn: 4 rows/call, 16 chunks/row
        int row = w * 16 + c * 4 + (lane >> 4);
        int cg = (lane & 15) ^ (row & 7);
        gld_lds16(kvb + (tokbase + row) * 4096 + h * 256 + cg * 8,
                  &Ksn[(w * 16 + c * 4) * 128]);
      }
#pragma unroll
      for (int c = 0; c < 2; c++) {  // Ksp: 8 rows/call, 8 chunks/row
        int row = w * 16 + c * 8 + (lane >> 3);
        int cg = (lane & 7) ^ (row & 7);
        gld_lds16(kpe + (tokbase + row) * kpe_stride + cg * 8,
                  &Ksp[(w * 16 + c * 8) * 64]);
      }
#pragma unroll
      for (int c = 0; c < 4; c++) {  // Vts: 8 vd-rows/call, 8 chunks/row
        int vd = w * 32 + c * 8 + (lane >> 3);
        int cg = (lane & 7) ^ (vd & 7);
        gld_lds16(vt + ((size_t)((b * 16 + h) * 128) + vd) * S + k0 + cg * 8,
                  &Vts[(w * 32 + c * 8) * 64]);
      }
      __syncthreads();

      // ---- S = Q K^T for wave's 16 rows x 64 keys ----
      floatx4 accs[4];
#pragma unroll
      for (int nt = 0; nt < 4; nt++) accs[nt] = (floatx4){0.f, 0.f, 0.f, 0.f};
#pragma unroll
      for (int nt = 0; nt < 4; nt++) {
#pragma unroll
        for (int ks = 0; ks < 4; ks++) {
          short8 bf = *(const short8*)&Ksn[(nt * 16 + fr) * 128 + ((ks * 4 + fq) ^ fs) * 8];
          accs[nt] = __builtin_amdgcn_mfma_f32_16x16x32_bf16(qfrag[ks], bf, accs[nt], 0, 0, 0);
        }
#pragma unroll
        for (int ks = 0; ks < 2; ks++) {
          short8 bf = *(const short8*)&Ksp[(nt * 16 + fr) * 64 + ((ks * 4 + fq) ^ fs) * 8];
          accs[nt] = __builtin_amdgcn_mfma_f32_16x16x32_bf16(qfrag[4 + ks], bf, accs[nt], 0, 0, 0);
        }
      }

      // ---- scale + causal mask (diagonal tile only) ----
      bool diag = (kt == qt);
#pragma unroll
      for (int nt = 0; nt < 4; nt++)
#pragma unroll
        for (int r = 0; r < 4; r++) {
          float s = accs[nt][r] * scale;
          if (diag) {
            int col = nt * 16 + fr;
            int row = fq * 4 + r;
            if (k0 + col > q0 + w * 16 + row) s = -3e38f;
          }
          accs[nt][r] = s;
        }

      // ---- in-register online softmax (max globally reduced; sum per-lane) --
      float alpha[4];
#pragma unroll
      for (int r = 0; r < 4; r++) {
        float mx = fmaxf(fmaxf(accs[0][r], accs[1][r]), fmaxf(accs[2][r], accs[3][r]));
        mx = fmaxf(mx, __shfl_xor(mx, 1));
        mx = fmaxf(mx, __shfl_xor(mx, 2));
        mx = fmaxf(mx, __shfl_xor(mx, 4));
        mx = fmaxf(mx, __shfl_xor(mx, 8));
        float mnew = fmaxf(m_r[r], mx);
        alpha[r] = __expf(m_r[r] - mnew);
        m_r[r] = mnew;
        l_r[r] *= alpha[r];
      }
#pragma unroll
      for (int nt = 0; nt < 4; nt++)
#pragma unroll
        for (int r = 0; r < 4; r++) {
          float pv = __expf(accs[nt][r] - m_r[r]);
          l_r[r] += pv;
          int row_p = w * 16 + fq * 4 + r;
          int col = nt * 16 + fr;
          Ps[row_p * 64 + (((col >> 3) ^ (row_p & 7)) * 8) + (col & 7)] = f2bf(pv);
        }
      __syncthreads();   // Ps visible to PV reads

      // ---- O = O*alpha + P V ----
#pragma unroll
      for (int j = 0; j < 8; j++)
#pragma unroll
        for (int r = 0; r < 4; r++) acc_o[j][r] *= alpha[r];
      short8 pf0 = *(const short8*)&Ps[(w * 16 + fr) * 64 + (fq ^ fs) * 8];
      short8 pf1 = *(const short8*)&Ps[(w * 16 + fr) * 64 + ((4 + fq) ^ fs) * 8];
#pragma unroll
      for (int j = 0; j < 8; j++) {
        short8 v0 = *(const short8*)&Vts[(j * 16 + fr) * 64 + (fq ^ fs) * 8];
        short8 v1 = *(const short8*)&Vts[(j * 16 + fr) * 64 + ((4 + fq) ^ fs) * 8];
        acc_o[j] = __builtin_amdgcn_mfma_f32_16x16x32_bf16(pf0, v0, acc_o[j], 0, 0, 0);
        acc_o[j] = __builtin_amdgcn_mfma_f32_16x16x32_bf16(pf1, v1, acc_o[j], 0, 0, 0);
      }
      __syncthreads();   // before next tile's staging overwrites LDS
    }

    // ---- epilogue: reduce per-lane l partials across the row's 16 lanes ----
    float inv_l[4];
#pragma unroll
    for (int r = 0; r < 4; r++) {
      float sm = l_r[r];
      sm += __shfl_xor(sm, 1);
      sm += __shfl_xor(sm, 2);
      sm += __shfl_xor(sm, 4);
      sm += __shfl_xor(sm, 8);
      inv_l[r] = 1.f / sm;
    }
#pragma unroll
    for (int j = 0; j < 8; j++)
#pragma unroll
      for (int r = 0; r < 4; r++) {
        size_t row = (size_t)(b * S + q0 + w * 16 + fq * 4 + r);
        at[row * 2048 + h * 128 + j * 16 + fr] = f2bf(acc_o[j][r] * inv_l[r]);
      }
  }
}

// ---------------------------------------------------------------------------
extern "C" void kernel_launch(void* const* d_in, const int* in_sizes, int n_in,
                              void* d_out, int out_size, void* d_ws, size_t ws_size,
                              hipStream_t stream) {
  (void)in_sizes; (void)n_in; (void)out_size; (void)ws_size;
  const float* x     = (const float*)d_in[0];
  const float* cosb  = (const float*)d_in[1];
  const float* sinb  = (const float*)d_in[2];
  const float* wq_a  = (const float*)d_in[3];
  const float* qnw   = (const float*)d_in[4];
  const float* wq_b  = (const float*)d_in[5];
  const float* wkv_a = (const float*)d_in[6];
  const float* kvnw  = (const float*)d_in[7];
  const float* wkv_b = (const float*)d_in[8];
  const float* wo    = (const float*)d_in[9];
  float* out = (float*)d_out;
  const int B = 2, S = 2048, T = B * S;

  char* wsb = (char*)d_ws;
  size_t off = 0;
  u16* xb   = (u16*)(wsb + off); off += (size_t)T * 2048 * 2;
  u16* wcat = (u16*)(wsb + off); off += (size_t)2176 * 2048 * 2;  // wq_a|wkv_a|pad
  u16* wqbb = (u16*)(wsb + off); off += (size_t)3072 * 1536 * 2;
  u16* wkbb = (u16*)(wsb + off); off += (size_t)4096 * 512 * 2;
  u16* wob  = (u16*)(wsb + off); off += (size_t)2048 * 2048 * 2;
  u16* qkv  = (u16*)(wsb + off); off += (size_t)T * 2176 * 2;     // qa|kv|kpe
  u16* qf   = (u16*)(wsb + off); off += (size_t)T * 3072 * 2;
  u16* kvb  = (u16*)(wsb + off); off += (size_t)T * 4096 * 2;
  u16* at   = (u16*)(wsb + off); off += (size_t)T * 2048 * 2;
  u16* vt   = xb;   // reuse: xb dead after GEMM 1; same size (T*2048)

  // 0) all repacks in one dispatch (regions sized <= 8.39M elems)
  repack_all_k<<<dim3(8192, 5), 256, 0, stream>>>(
      x, wq_a, wkv_a, wq_b, wkv_b, wo, xb, wcat, wqbb, wkbb, wob);

  // 1) qkv = xb @ [wq_a;wkv_a]^T   [T,2176]  (qa | kv | kpe | pad)
  gemm_bt_mfma<0><<<dim3(2176 / 128, T / 128), 256, 0, stream>>>(xb, 2048, wcat, 2048, qkv, 2176, 2048);
  // 2) fused: rmsnorm(qa), rmsnorm(kv), rope(kpe)
  normrope_k<<<T, 256, 0, stream>>>(qkv, qnw, kvnw, cosb, sinb, S);
  // 3) merged: qf = qa @ wq_b^T [T,3072]  AND  kvb = kv @ wkv_b^T [T,4096]
  gemm_dual_mfma<<<dim3(3072 / 128 + 4096 / 128, T / 128), 256, 0, stream>>>(
      qkv, 2176, wqbb, 1536, qf, 3072, 1536, 3072 / 128,
      qkv + 1536, 2176, wkbb, 512, kvb, 4096, 512);
  // 4) rope q_pe per head
  rope_k<<<dim3(T, 16), 32, 0, stream>>>(qf, 3072, 192, 128, cosb, sinb, S);
  // 5) V transpose (vt overlays dead xb)
  vtrans_k<<<dim3(S / 64, 16, B), 256, 0, stream>>>(kvb, vt, S);
  // 6) MFMA flash attention (paired q-tiles, XCD-grouped) -> at [T,2048]
  attn_mfma<<<dim3((S / 128) * 32), 256, 0, stream>>>(qf, kvb, qkv + 2048, 2176, vt, at, S);
  // 7) out = at @ wo^T [T,2048] fp32
  gemm_bt_mfma<1><<<dim3(2048 / 128, T / 128), 256, 0, stream>>>(at, 2048, wob, 2048, out, 2048, 2048);
}